// Round 1
// baseline (5026.683 us; speedup 1.0000x reference)
//
#include <hip/hip_runtime.h>
#include <math.h>

// ---------------------------------------------------------------------------
// CDAttnBlock: y_i = attn_i(...) @ Wout + bout, for
//   attn1(q1,k1,v1), attn2(q2,k2,v2), attn3(q1,k2,v2)
// fp32 baseline (round 0): tiled vector GEMMs + flash attention.
//
// Workspace layout (floats):
//   [0..6*QKV)    : q1,k1,v1,q2,k2,v2   each [b,h,s,d] = 6,291,456 floats
//   [6*QKV..9*QKV): o_all [3*8192, 768] (row = attn*8192 + b*1024 + s,
//                                        col = h*64 + d)
//   total 56,623,104 floats = 226.5 MB  (requires ws_size >= that)
// ---------------------------------------------------------------------------

#define HIDDEN 768
#define NH 12
#define HD 64
#define BB 8
#define SS 1024
#define ATT_SCALE 0.125f

constexpr int MROWS   = BB * SS;          // 8192 rows per input
constexpr int M_QKV   = 2 * MROWS;        // 16384
constexpr int N_QKV   = 3 * HIDDEN;       // 2304
constexpr long QKV_ELEMS = (long)BB * NH * SS * HD;  // 6,291,456

// ---------------------------------------------------------------------------
// GEMM 1: C[m, n] = [x;x2][m, k] * Wqkv[k, n], scattered to q/k/v buffers.
// 64x64 tile, 256 threads, 4x4 micro-tile, K-tile 32.
// ---------------------------------------------------------------------------
__global__ __launch_bounds__(256) void gemm_qkv_kernel(
    const float* __restrict__ x, const float* __restrict__ x2,
    const float* __restrict__ W, float* __restrict__ ws)
{
    __shared__ float As[32][65];   // [k][m] transposed, pad 65 -> CF writes
    __shared__ float Bs[32][68];   // [k][n]

    const int bm = blockIdx.x;         // 0..255
    const int bn = blockIdx.y;         // 0..35
    const int tid = threadIdx.x;
    const int tx = tid & 15, ty = tid >> 4;
    const int m0 = bm * 64, n0 = bn * 64;
    const int inp = (m0 < MROWS) ? 0 : 1;
    const float* __restrict__ A = inp ? x2 : x;
    const int mbase = m0 & (MROWS - 1);

    float acc[4][4] = {};

    for (int k0 = 0; k0 < HIDDEN; k0 += 32) {
        {   // A tile 64 rows x 32 k, store transposed As[k][m]
            const int r  = tid >> 3;          // 0..31
            const int kk = (tid & 7) * 4;     // 0..28
            #pragma unroll
            for (int rr = 0; rr < 2; ++rr) {
                const float4 v = *(const float4*)&A[(size_t)(mbase + r + rr * 32) * HIDDEN + k0 + kk];
                As[kk + 0][r + rr * 32] = v.x;
                As[kk + 1][r + rr * 32] = v.y;
                As[kk + 2][r + rr * 32] = v.z;
                As[kk + 3][r + rr * 32] = v.w;
            }
        }
        {   // B tile 32 k x 64 n
            const int kr = tid >> 4;          // 0..15
            const int nn = (tid & 15) * 4;
            #pragma unroll
            for (int rr = 0; rr < 2; ++rr) {
                *(float4*)&Bs[kr + rr * 16][nn] =
                    *(const float4*)&W[(size_t)(k0 + kr + rr * 16) * N_QKV + n0 + nn];
            }
        }
        __syncthreads();
        #pragma unroll
        for (int k = 0; k < 32; ++k) {
            const float a0 = As[k][4 * ty + 0];
            const float a1 = As[k][4 * ty + 1];
            const float a2 = As[k][4 * ty + 2];
            const float a3 = As[k][4 * ty + 3];
            const float4 b = *(const float4*)&Bs[k][4 * tx];
            acc[0][0] = fmaf(a0, b.x, acc[0][0]); acc[0][1] = fmaf(a0, b.y, acc[0][1]);
            acc[0][2] = fmaf(a0, b.z, acc[0][2]); acc[0][3] = fmaf(a0, b.w, acc[0][3]);
            acc[1][0] = fmaf(a1, b.x, acc[1][0]); acc[1][1] = fmaf(a1, b.y, acc[1][1]);
            acc[1][2] = fmaf(a1, b.z, acc[1][2]); acc[1][3] = fmaf(a1, b.w, acc[1][3]);
            acc[2][0] = fmaf(a2, b.x, acc[2][0]); acc[2][1] = fmaf(a2, b.y, acc[2][1]);
            acc[2][2] = fmaf(a2, b.z, acc[2][2]); acc[2][3] = fmaf(a2, b.w, acc[2][3]);
            acc[3][0] = fmaf(a3, b.x, acc[3][0]); acc[3][1] = fmaf(a3, b.y, acc[3][1]);
            acc[3][2] = fmaf(a3, b.z, acc[3][2]); acc[3][3] = fmaf(a3, b.w, acc[3][3]);
        }
        __syncthreads();
    }

    // Epilogue: tile's 64 n-columns sit inside exactly one (qkv, head).
    const int sel = n0 / HIDDEN;              // 0=q 1=k 2=v
    const int h   = (n0 % HIDDEN) / HD;       // head
    const int d0  = 4 * tx;                   // d within head
    float* __restrict__ buf = ws + (size_t)(inp * 3 + sel) * QKV_ELEMS;
    #pragma unroll
    for (int i = 0; i < 4; ++i) {
        const int g  = mbase + 4 * ty + i;    // row within this input
        const int bb = g >> 10, ssr = g & (SS - 1);
        *(float4*)&buf[(((size_t)bb * NH + h) * SS + ssr) * HD + d0] =
            make_float4(acc[i][0], acc[i][1], acc[i][2], acc[i][3]);
    }
}

// ---------------------------------------------------------------------------
// Flash attention, fp32. One q-row per lane; 256 threads handle 256 q-rows.
// grid = (S/256, B*NH, 3). K/V tiles (64 keys) staged in LDS, broadcast-read.
// Writes o in [attn][b][s][h*64+d] layout (rows of the out-proj GEMM).
// ---------------------------------------------------------------------------
__global__ __launch_bounds__(256, 2) void attn_kernel(float* __restrict__ ws)
{
    __shared__ float Ks[64][68];
    __shared__ float Vs[64][68];

    const int tid = threadIdx.x;
    const int qt  = blockIdx.x;           // 0..3
    const int bh  = blockIdx.y;           // 0..95
    const int aid = blockIdx.z;           // 0..2

    const float* __restrict__ qbuf = ws + (size_t)((aid == 1) ? 3 : 0) * QKV_ELEMS;
    const float* __restrict__ kbuf = ws + (size_t)((aid == 0) ? 1 : 4) * QKV_ELEMS;
    const float* __restrict__ vbuf = ws + (size_t)((aid == 0) ? 2 : 5) * QKV_ELEMS;
    float* __restrict__ o_all = ws + (size_t)6 * QKV_ELEMS;

    const size_t base = (size_t)bh * SS * HD;
    const int row = qt * 256 + tid;
    const int b = bh / NH, h = bh % NH;

    float4 q4[16];
    {
        const float* __restrict__ qrow = qbuf + base + (size_t)row * HD;
        #pragma unroll
        for (int i = 0; i < 16; ++i) q4[i] = *(const float4*)&qrow[4 * i];
    }
    float4 o4[16];
    #pragma unroll
    for (int i = 0; i < 16; ++i) o4[i] = make_float4(0.f, 0.f, 0.f, 0.f);
    float mrun = -INFINITY, lrun = 0.f;

    for (int kt = 0; kt < SS; kt += 64) {
        __syncthreads();   // previous tile fully consumed before overwrite
        {   // stage K,V: 64 rows x 64 floats each
            const int jr = tid >> 4;             // 0..15
            const int d4 = (tid & 15) * 4;
            #pragma unroll
            for (int rr = 0; rr < 4; ++rr) {
                const int j = jr + rr * 16;
                *(float4*)&Ks[j][d4] = *(const float4*)&kbuf[base + (size_t)(kt + j) * HD + d4];
                *(float4*)&Vs[j][d4] = *(const float4*)&vbuf[base + (size_t)(kt + j) * HD + d4];
            }
        }
        __syncthreads();

        float sc[64];
        float tmax = -INFINITY;
        #pragma unroll
        for (int j = 0; j < 64; ++j) {
            float ax = 0.f, ay = 0.f, az = 0.f, aw = 0.f;
            #pragma unroll
            for (int i = 0; i < 16; ++i) {
                const float4 kv = *(const float4*)&Ks[j][4 * i];
                ax = fmaf(q4[i].x, kv.x, ax);
                ay = fmaf(q4[i].y, kv.y, ay);
                az = fmaf(q4[i].z, kv.z, az);
                aw = fmaf(q4[i].w, kv.w, aw);
            }
            const float s = ((ax + ay) + (az + aw)) * ATT_SCALE;
            sc[j] = s;
            tmax = fmaxf(tmax, s);
        }

        const float mnew = fmaxf(mrun, tmax);
        const float corr = __expf(mrun - mnew);
        lrun *= corr;
        #pragma unroll
        for (int i = 0; i < 16; ++i) {
            o4[i].x *= corr; o4[i].y *= corr; o4[i].z *= corr; o4[i].w *= corr;
        }
        #pragma unroll
        for (int j = 0; j < 64; ++j) {
            const float p = __expf(sc[j] - mnew);
            lrun += p;
            #pragma unroll
            for (int i = 0; i < 16; ++i) {
                const float4 vv = *(const float4*)&Vs[j][4 * i];
                o4[i].x = fmaf(p, vv.x, o4[i].x);
                o4[i].y = fmaf(p, vv.y, o4[i].y);
                o4[i].z = fmaf(p, vv.z, o4[i].z);
                o4[i].w = fmaf(p, vv.w, o4[i].w);
            }
        }
        mrun = mnew;
    }

    const float inv = 1.f / lrun;
    float* __restrict__ orow =
        o_all + ((size_t)(aid * MROWS + b * SS + row)) * HIDDEN + h * HD;
    #pragma unroll
    for (int i = 0; i < 16; ++i) {
        *(float4*)&orow[4 * i] =
            make_float4(o4[i].x * inv, o4[i].y * inv, o4[i].z * inv, o4[i].w * inv);
    }
}

// ---------------------------------------------------------------------------
// GEMM 2: out[m, n] = o_all[m, k] * Wout[k, n] + bout[n], m in [0, 24576)
// ---------------------------------------------------------------------------
__global__ __launch_bounds__(256) void gemm_out_kernel(
    const float* __restrict__ A, const float* __restrict__ W,
    const float* __restrict__ bias, float* __restrict__ out)
{
    __shared__ float As[32][65];
    __shared__ float Bs[32][68];

    const int bm = blockIdx.x;          // 0..383
    const int bn = blockIdx.y;          // 0..11
    const int tid = threadIdx.x;
    const int tx = tid & 15, ty = tid >> 4;
    const int m0 = bm * 64, n0 = bn * 64;

    float acc[4][4] = {};

    for (int k0 = 0; k0 < HIDDEN; k0 += 32) {
        {
            const int r  = tid >> 3;
            const int kk = (tid & 7) * 4;
            #pragma unroll
            for (int rr = 0; rr < 2; ++rr) {
                const float4 v = *(const float4*)&A[(size_t)(m0 + r + rr * 32) * HIDDEN + k0 + kk];
                As[kk + 0][r + rr * 32] = v.x;
                As[kk + 1][r + rr * 32] = v.y;
                As[kk + 2][r + rr * 32] = v.z;
                As[kk + 3][r + rr * 32] = v.w;
            }
        }
        {
            const int kr = tid >> 4;
            const int nn = (tid & 15) * 4;
            #pragma unroll
            for (int rr = 0; rr < 2; ++rr) {
                *(float4*)&Bs[kr + rr * 16][nn] =
                    *(const float4*)&W[(size_t)(k0 + kr + rr * 16) * HIDDEN + n0 + nn];
            }
        }
        __syncthreads();
        #pragma unroll
        for (int k = 0; k < 32; ++k) {
            const float a0 = As[k][4 * ty + 0];
            const float a1 = As[k][4 * ty + 1];
            const float a2 = As[k][4 * ty + 2];
            const float a3 = As[k][4 * ty + 3];
            const float4 b = *(const float4*)&Bs[k][4 * tx];
            acc[0][0] = fmaf(a0, b.x, acc[0][0]); acc[0][1] = fmaf(a0, b.y, acc[0][1]);
            acc[0][2] = fmaf(a0, b.z, acc[0][2]); acc[0][3] = fmaf(a0, b.w, acc[0][3]);
            acc[1][0] = fmaf(a1, b.x, acc[1][0]); acc[1][1] = fmaf(a1, b.y, acc[1][1]);
            acc[1][2] = fmaf(a1, b.z, acc[1][2]); acc[1][3] = fmaf(a1, b.w, acc[1][3]);
            acc[2][0] = fmaf(a2, b.x, acc[2][0]); acc[2][1] = fmaf(a2, b.y, acc[2][1]);
            acc[2][2] = fmaf(a2, b.z, acc[2][2]); acc[2][3] = fmaf(a2, b.w, acc[2][3]);
            acc[3][0] = fmaf(a3, b.x, acc[3][0]); acc[3][1] = fmaf(a3, b.y, acc[3][1]);
            acc[3][2] = fmaf(a3, b.z, acc[3][2]); acc[3][3] = fmaf(a3, b.w, acc[3][3]);
        }
        __syncthreads();
    }

    const int nn = n0 + 4 * tx;
    const float4 bv = *(const float4*)&bias[nn];
    #pragma unroll
    for (int i = 0; i < 4; ++i) {
        const int m = m0 + 4 * ty + i;
        *(float4*)&out[(size_t)m * HIDDEN + nn] =
            make_float4(acc[i][0] + bv.x, acc[i][1] + bv.y,
                        acc[i][2] + bv.z, acc[i][3] + bv.w);
    }
}

// ---------------------------------------------------------------------------
extern "C" void kernel_launch(void* const* d_in, const int* in_sizes, int n_in,
                              void* d_out, int out_size, void* d_ws, size_t ws_size,
                              hipStream_t stream)
{
    const float* x    = (const float*)d_in[0];
    const float* x2   = (const float*)d_in[1];
    const float* Wqkv = (const float*)d_in[2];
    const float* Wout = (const float*)d_in[3];
    const float* bout = (const float*)d_in[4];
    float* ws  = (float*)d_ws;
    float* out = (float*)d_out;
    float* o_all = ws + (size_t)6 * QKV_ELEMS;

    dim3 g1(M_QKV / 64, N_QKV / 64);           // 256 x 36
    gemm_qkv_kernel<<<g1, 256, 0, stream>>>(x, x2, Wqkv, ws);

    dim3 g2(SS / 256, BB * NH, 3);             // 4 x 96 x 3
    attn_kernel<<<g2, 256, 0, stream>>>(ws);

    dim3 g3(3 * MROWS / 64, HIDDEN / 64);      // 384 x 12
    gemm_out_kernel<<<g3, 256, 0, stream>>>(o_all, Wout, bout, out);
}

// Round 2
// 3999.883 us; speedup vs baseline: 1.2567x; 1.2567x over previous
//
#include <hip/hip_runtime.h>
#include <math.h>

// ---------------------------------------------------------------------------
// CDAttnBlock: y_i = attn_i(...) @ Wout + bout, for
//   attn1(q1,k1,v1), attn2(q2,k2,v2), attn3(q1,k2,v2)
// Round 1: fp32; attention de-spilled (score chunk 16, waves_per_eu pinned).
//
// Workspace layout (floats):
//   [0..6*QKV)    : q1,k1,v1,q2,k2,v2   each [b,h,s,d] = 6,291,456 floats
//   [6*QKV..9*QKV): o_all [3*8192, 768]
// ---------------------------------------------------------------------------

#define HIDDEN 768
#define NH 12
#define HD 64
#define BB 8
#define SS 1024
#define ATT_SCALE 0.125f

constexpr int MROWS   = BB * SS;          // 8192 rows per input
constexpr int M_QKV   = 2 * MROWS;        // 16384
constexpr int N_QKV   = 3 * HIDDEN;       // 2304
constexpr long QKV_ELEMS = (long)BB * NH * SS * HD;  // 6,291,456

// ---------------------------------------------------------------------------
// GEMM 1: C[m, n] = [x;x2][m, k] * Wqkv[k, n], scattered to q/k/v buffers.
// ---------------------------------------------------------------------------
__global__ __launch_bounds__(256) void gemm_qkv_kernel(
    const float* __restrict__ x, const float* __restrict__ x2,
    const float* __restrict__ W, float* __restrict__ ws)
{
    __shared__ float As[32][65];
    __shared__ float Bs[32][68];

    const int bm = blockIdx.x;
    const int bn = blockIdx.y;
    const int tid = threadIdx.x;
    const int tx = tid & 15, ty = tid >> 4;
    const int m0 = bm * 64, n0 = bn * 64;
    const int inp = (m0 < MROWS) ? 0 : 1;
    const float* __restrict__ A = inp ? x2 : x;
    const int mbase = m0 & (MROWS - 1);

    float acc[4][4] = {};

    for (int k0 = 0; k0 < HIDDEN; k0 += 32) {
        {
            const int r  = tid >> 3;
            const int kk = (tid & 7) * 4;
            #pragma unroll
            for (int rr = 0; rr < 2; ++rr) {
                const float4 v = *(const float4*)&A[(size_t)(mbase + r + rr * 32) * HIDDEN + k0 + kk];
                As[kk + 0][r + rr * 32] = v.x;
                As[kk + 1][r + rr * 32] = v.y;
                As[kk + 2][r + rr * 32] = v.z;
                As[kk + 3][r + rr * 32] = v.w;
            }
        }
        {
            const int kr = tid >> 4;
            const int nn = (tid & 15) * 4;
            #pragma unroll
            for (int rr = 0; rr < 2; ++rr) {
                *(float4*)&Bs[kr + rr * 16][nn] =
                    *(const float4*)&W[(size_t)(k0 + kr + rr * 16) * N_QKV + n0 + nn];
            }
        }
        __syncthreads();
        #pragma unroll
        for (int k = 0; k < 32; ++k) {
            const float a0 = As[k][4 * ty + 0];
            const float a1 = As[k][4 * ty + 1];
            const float a2 = As[k][4 * ty + 2];
            const float a3 = As[k][4 * ty + 3];
            const float4 b = *(const float4*)&Bs[k][4 * tx];
            acc[0][0] = fmaf(a0, b.x, acc[0][0]); acc[0][1] = fmaf(a0, b.y, acc[0][1]);
            acc[0][2] = fmaf(a0, b.z, acc[0][2]); acc[0][3] = fmaf(a0, b.w, acc[0][3]);
            acc[1][0] = fmaf(a1, b.x, acc[1][0]); acc[1][1] = fmaf(a1, b.y, acc[1][1]);
            acc[1][2] = fmaf(a1, b.z, acc[1][2]); acc[1][3] = fmaf(a1, b.w, acc[1][3]);
            acc[2][0] = fmaf(a2, b.x, acc[2][0]); acc[2][1] = fmaf(a2, b.y, acc[2][1]);
            acc[2][2] = fmaf(a2, b.z, acc[2][2]); acc[2][3] = fmaf(a2, b.w, acc[2][3]);
            acc[3][0] = fmaf(a3, b.x, acc[3][0]); acc[3][1] = fmaf(a3, b.y, acc[3][1]);
            acc[3][2] = fmaf(a3, b.z, acc[3][2]); acc[3][3] = fmaf(a3, b.w, acc[3][3]);
        }
        __syncthreads();
    }

    const int sel = n0 / HIDDEN;
    const int h   = (n0 % HIDDEN) / HD;
    const int d0  = 4 * tx;
    float* __restrict__ buf = ws + (size_t)(inp * 3 + sel) * QKV_ELEMS;
    #pragma unroll
    for (int i = 0; i < 4; ++i) {
        const int g  = mbase + 4 * ty + i;
        const int bb = g >> 10, ssr = g & (SS - 1);
        *(float4*)&buf[(((size_t)bb * NH + h) * SS + ssr) * HD + d0] =
            make_float4(acc[i][0], acc[i][1], acc[i][2], acc[i][3]);
    }
}

// ---------------------------------------------------------------------------
// Flash attention, fp32. One q-row per lane. Score chunk = 16 keys so live
// state is q4(64) + o4(64) + sc(16) ~= 170 VGPRs.
// amdgpu_waves_per_eu(2,2) pins the allocator to a 256-VGPR budget so it
// does NOT trade spills for occupancy (round-0 lesson: launch_bounds min
// waves let it pick 128 VGPR + 4.4 GB of scratch traffic).
// ---------------------------------------------------------------------------
__global__ __launch_bounds__(256)
__attribute__((amdgpu_waves_per_eu(2, 2)))
void attn_kernel(float* __restrict__ ws)
{
    __shared__ float Ks[64][68];
    __shared__ float Vs[64][68];

    const int tid = threadIdx.x;
    const int qt  = blockIdx.x;           // 0..3
    const int bh  = blockIdx.y;           // 0..95
    const int aid = blockIdx.z;           // 0..2

    const float* __restrict__ qbuf = ws + (size_t)((aid == 1) ? 3 : 0) * QKV_ELEMS;
    const float* __restrict__ kbuf = ws + (size_t)((aid == 0) ? 1 : 4) * QKV_ELEMS;
    const float* __restrict__ vbuf = ws + (size_t)((aid == 0) ? 2 : 5) * QKV_ELEMS;
    float* __restrict__ o_all = ws + (size_t)6 * QKV_ELEMS;

    const size_t base = (size_t)bh * SS * HD;
    const int row = qt * 256 + tid;
    const int b = bh / NH, h = bh % NH;

    float4 q4[16];
    {
        const float* __restrict__ qrow = qbuf + base + (size_t)row * HD;
        #pragma unroll
        for (int i = 0; i < 16; ++i) q4[i] = *(const float4*)&qrow[4 * i];
    }
    float4 o4[16];
    #pragma unroll
    for (int i = 0; i < 16; ++i) o4[i] = make_float4(0.f, 0.f, 0.f, 0.f);
    float mrun = -INFINITY, lrun = 0.f;

    for (int kt = 0; kt < SS; kt += 64) {
        __syncthreads();
        {   // stage K,V: 64 rows x 64 floats each
            const int jr = tid >> 4;
            const int d4 = (tid & 15) * 4;
            #pragma unroll
            for (int rr = 0; rr < 4; ++rr) {
                const int j = jr + rr * 16;
                *(float4*)&Ks[j][d4] = *(const float4*)&kbuf[base + (size_t)(kt + j) * HD + d4];
                *(float4*)&Vs[j][d4] = *(const float4*)&vbuf[base + (size_t)(kt + j) * HD + d4];
            }
        }
        __syncthreads();

        #pragma unroll
        for (int c = 0; c < 4; ++c) {     // 16-key chunks: bounded live state
            float sc[16];
            float tmax = -INFINITY;
            #pragma unroll
            for (int jj = 0; jj < 16; ++jj) {
                const int j = c * 16 + jj;
                float ax = 0.f, ay = 0.f, az = 0.f, aw = 0.f;
                #pragma unroll
                for (int i = 0; i < 16; ++i) {
                    const float4 kv = *(const float4*)&Ks[j][4 * i];
                    ax = fmaf(q4[i].x, kv.x, ax);
                    ay = fmaf(q4[i].y, kv.y, ay);
                    az = fmaf(q4[i].z, kv.z, az);
                    aw = fmaf(q4[i].w, kv.w, aw);
                }
                const float s = ((ax + ay) + (az + aw)) * ATT_SCALE;
                sc[jj] = s;
                tmax = fmaxf(tmax, s);
            }

            const float mnew = fmaxf(mrun, tmax);
            const float corr = __expf(mrun - mnew);
            lrun *= corr;
            #pragma unroll
            for (int i = 0; i < 16; ++i) {
                o4[i].x *= corr; o4[i].y *= corr; o4[i].z *= corr; o4[i].w *= corr;
            }
            #pragma unroll
            for (int jj = 0; jj < 16; ++jj) {
                const int j = c * 16 + jj;
                const float p = __expf(sc[jj] - mnew);
                lrun += p;
                #pragma unroll
                for (int i = 0; i < 16; ++i) {
                    const float4 vv = *(const float4*)&Vs[j][4 * i];
                    o4[i].x = fmaf(p, vv.x, o4[i].x);
                    o4[i].y = fmaf(p, vv.y, o4[i].y);
                    o4[i].z = fmaf(p, vv.z, o4[i].z);
                    o4[i].w = fmaf(p, vv.w, o4[i].w);
                }
            }
            mrun = mnew;
        }
    }

    const float inv = 1.f / lrun;
    float* __restrict__ orow =
        o_all + ((size_t)(aid * MROWS + b * SS + row)) * HIDDEN + h * HD;
    #pragma unroll
    for (int i = 0; i < 16; ++i) {
        *(float4*)&orow[4 * i] =
            make_float4(o4[i].x * inv, o4[i].y * inv, o4[i].z * inv, o4[i].w * inv);
    }
}

// ---------------------------------------------------------------------------
// GEMM 2: out[m, n] = o_all[m, k] * Wout[k, n] + bout[n]
// ---------------------------------------------------------------------------
__global__ __launch_bounds__(256) void gemm_out_kernel(
    const float* __restrict__ A, const float* __restrict__ W,
    const float* __restrict__ bias, float* __restrict__ out)
{
    __shared__ float As[32][65];
    __shared__ float Bs[32][68];

    const int bm = blockIdx.x;
    const int bn = blockIdx.y;
    const int tid = threadIdx.x;
    const int tx = tid & 15, ty = tid >> 4;
    const int m0 = bm * 64, n0 = bn * 64;

    float acc[4][4] = {};

    for (int k0 = 0; k0 < HIDDEN; k0 += 32) {
        {
            const int r  = tid >> 3;
            const int kk = (tid & 7) * 4;
            #pragma unroll
            for (int rr = 0; rr < 2; ++rr) {
                const float4 v = *(const float4*)&A[(size_t)(m0 + r + rr * 32) * HIDDEN + k0 + kk];
                As[kk + 0][r + rr * 32] = v.x;
                As[kk + 1][r + rr * 32] = v.y;
                As[kk + 2][r + rr * 32] = v.z;
                As[kk + 3][r + rr * 32] = v.w;
            }
        }
        {
            const int kr = tid >> 4;
            const int nn = (tid & 15) * 4;
            #pragma unroll
            for (int rr = 0; rr < 2; ++rr) {
                *(float4*)&Bs[kr + rr * 16][nn] =
                    *(const float4*)&W[(size_t)(k0 + kr + rr * 16) * HIDDEN + n0 + nn];
            }
        }
        __syncthreads();
        #pragma unroll
        for (int k = 0; k < 32; ++k) {
            const float a0 = As[k][4 * ty + 0];
            const float a1 = As[k][4 * ty + 1];
            const float a2 = As[k][4 * ty + 2];
            const float a3 = As[k][4 * ty + 3];
            const float4 b = *(const float4*)&Bs[k][4 * tx];
            acc[0][0] = fmaf(a0, b.x, acc[0][0]); acc[0][1] = fmaf(a0, b.y, acc[0][1]);
            acc[0][2] = fmaf(a0, b.z, acc[0][2]); acc[0][3] = fmaf(a0, b.w, acc[0][3]);
            acc[1][0] = fmaf(a1, b.x, acc[1][0]); acc[1][1] = fmaf(a1, b.y, acc[1][1]);
            acc[1][2] = fmaf(a1, b.z, acc[1][2]); acc[1][3] = fmaf(a1, b.w, acc[1][3]);
            acc[2][0] = fmaf(a2, b.x, acc[2][0]); acc[2][1] = fmaf(a2, b.y, acc[2][1]);
            acc[2][2] = fmaf(a2, b.z, acc[2][2]); acc[2][3] = fmaf(a2, b.w, acc[2][3]);
            acc[3][0] = fmaf(a3, b.x, acc[3][0]); acc[3][1] = fmaf(a3, b.y, acc[3][1]);
            acc[3][2] = fmaf(a3, b.z, acc[3][2]); acc[3][3] = fmaf(a3, b.w, acc[3][3]);
        }
        __syncthreads();
    }

    const int nn = n0 + 4 * tx;
    const float4 bv = *(const float4*)&bias[nn];
    #pragma unroll
    for (int i = 0; i < 4; ++i) {
        const int m = m0 + 4 * ty + i;
        *(float4*)&out[(size_t)m * HIDDEN + nn] =
            make_float4(acc[i][0] + bv.x, acc[i][1] + bv.y,
                        acc[i][2] + bv.z, acc[i][3] + bv.w);
    }
}

// ---------------------------------------------------------------------------
extern "C" void kernel_launch(void* const* d_in, const int* in_sizes, int n_in,
                              void* d_out, int out_size, void* d_ws, size_t ws_size,
                              hipStream_t stream)
{
    const float* x    = (const float*)d_in[0];
    const float* x2   = (const float*)d_in[1];
    const float* Wqkv = (const float*)d_in[2];
    const float* Wout = (const float*)d_in[3];
    const float* bout = (const float*)d_in[4];
    float* ws  = (float*)d_ws;
    float* out = (float*)d_out;
    float* o_all = ws + (size_t)6 * QKV_ELEMS;

    dim3 g1(M_QKV / 64, N_QKV / 64);           // 256 x 36
    gemm_qkv_kernel<<<g1, 256, 0, stream>>>(x, x2, Wqkv, ws);

    dim3 g2(SS / 256, BB * NH, 3);             // 4 x 96 x 3
    attn_kernel<<<g2, 256, 0, stream>>>(ws);

    dim3 g3(3 * MROWS / 64, HIDDEN / 64);      // 384 x 12
    gemm_out_kernel<<<g3, 256, 0, stream>>>(o_all, Wout, bout, out);
}

// Round 5
// 1749.620 us; speedup vs baseline: 2.8730x; 2.2861x over previous
//
#include <hip/hip_runtime.h>
#include <math.h>

// ---------------------------------------------------------------------------
// CDAttnBlock round 3 kernel (resubmit x2; benches timed out on acquisition):
// attention -> MFMA split-bf16 (hi/lo, 3 mfma/product).
// GEMM1 epilogue now writes q/k/v as bf16 hi/lo planes; GEMMs still fp32.
//
// Workspace layout:
//   [0 .. 12*QKV) u16   : planes [inp][q/k/v][hi/lo]  (12 x 12.6 MB = 151 MB)
//   then o_all fp32     : [3*8192][768]               (75.5 MB)
// ---------------------------------------------------------------------------

#define HIDDEN 768
#define NH 12
#define HD 64
#define BB 8
#define SS 1024
#define ATT_SCALE 0.125f

typedef unsigned short u16;
typedef unsigned int u32;
typedef __attribute__((ext_vector_type(8))) short short8;   // 8 bf16
typedef __attribute__((ext_vector_type(4))) float f32x4;

constexpr int MROWS = BB * SS;            // 8192
constexpr int M_QKV = 2 * MROWS;          // 16384
constexpr int N_QKV = 3 * HIDDEN;         // 2304
constexpr long QKV_ELEMS = (long)BB * NH * SS * HD;  // 6,291,456

__device__ inline u16 f2bf(float x) {     // fp32 -> bf16 RTN
    u32 u = __float_as_uint(x);
    return (u16)((u + 0x7FFFu + ((u >> 16) & 1u)) >> 16);
}
__device__ inline float bf2f(u16 h) { return __uint_as_float(((u32)h) << 16); }
// XOR swizzle: spreads 128B-stride rows across 8 bank slots (G4 fix)
__device__ inline int swz(int row, int bcol) {
    return ((row << 7) + bcol) ^ ((row & 7) << 4);
}
#define MFMA16(a, b, c) __builtin_amdgcn_mfma_f32_16x16x32_bf16(a, b, c, 0, 0, 0)

// ---------------------------------------------------------------------------
// GEMM 1: [x;x2] @ Wqkv -> bf16 hi/lo planes in [b,h,s,d] layout.
// ---------------------------------------------------------------------------
__global__ __launch_bounds__(256) void gemm_qkv_kernel(
    const float* __restrict__ x, const float* __restrict__ x2,
    const float* __restrict__ W, u16* __restrict__ planes)
{
    __shared__ float As[32][65];
    __shared__ float Bs[32][68];

    const int bm = blockIdx.x;
    const int bn = blockIdx.y;
    const int tid = threadIdx.x;
    const int tx = tid & 15, ty = tid >> 4;
    const int m0 = bm * 64, n0 = bn * 64;
    const int inp = (m0 < MROWS) ? 0 : 1;
    const float* __restrict__ A = inp ? x2 : x;
    const int mbase = m0 & (MROWS - 1);

    float acc[4][4] = {};

    for (int k0 = 0; k0 < HIDDEN; k0 += 32) {
        {
            const int r  = tid >> 3;
            const int kk = (tid & 7) * 4;
            #pragma unroll
            for (int rr = 0; rr < 2; ++rr) {
                const float4 v = *(const float4*)&A[(size_t)(mbase + r + rr * 32) * HIDDEN + k0 + kk];
                As[kk + 0][r + rr * 32] = v.x;
                As[kk + 1][r + rr * 32] = v.y;
                As[kk + 2][r + rr * 32] = v.z;
                As[kk + 3][r + rr * 32] = v.w;
            }
        }
        {
            const int kr = tid >> 4;
            const int nn = (tid & 15) * 4;
            #pragma unroll
            for (int rr = 0; rr < 2; ++rr) {
                *(float4*)&Bs[kr + rr * 16][nn] =
                    *(const float4*)&W[(size_t)(k0 + kr + rr * 16) * N_QKV + n0 + nn];
            }
        }
        __syncthreads();
        #pragma unroll
        for (int k = 0; k < 32; ++k) {
            const float a0 = As[k][4 * ty + 0];
            const float a1 = As[k][4 * ty + 1];
            const float a2 = As[k][4 * ty + 2];
            const float a3 = As[k][4 * ty + 3];
            const float4 b = *(const float4*)&Bs[k][4 * tx];
            acc[0][0] = fmaf(a0, b.x, acc[0][0]); acc[0][1] = fmaf(a0, b.y, acc[0][1]);
            acc[0][2] = fmaf(a0, b.z, acc[0][2]); acc[0][3] = fmaf(a0, b.w, acc[0][3]);
            acc[1][0] = fmaf(a1, b.x, acc[1][0]); acc[1][1] = fmaf(a1, b.y, acc[1][1]);
            acc[1][2] = fmaf(a1, b.z, acc[1][2]); acc[1][3] = fmaf(a1, b.w, acc[1][3]);
            acc[2][0] = fmaf(a2, b.x, acc[2][0]); acc[2][1] = fmaf(a2, b.y, acc[2][1]);
            acc[2][2] = fmaf(a2, b.z, acc[2][2]); acc[2][3] = fmaf(a2, b.w, acc[2][3]);
            acc[3][0] = fmaf(a3, b.x, acc[3][0]); acc[3][1] = fmaf(a3, b.y, acc[3][1]);
            acc[3][2] = fmaf(a3, b.z, acc[3][2]); acc[3][3] = fmaf(a3, b.w, acc[3][3]);
        }
        __syncthreads();
    }

    // Epilogue: split each value into bf16 hi + lo, write 8B per plane.
    const int sel = n0 / HIDDEN;
    const int h   = (n0 % HIDDEN) / HD;
    const int d0  = 4 * tx;
    u16* __restrict__ ph = planes + (size_t)(inp * 6 + sel * 2) * QKV_ELEMS;
    u16* __restrict__ pl = ph + QKV_ELEMS;
    #pragma unroll
    for (int i = 0; i < 4; ++i) {
        const int g  = mbase + 4 * ty + i;
        const int bb = g >> 10, ssr = g & (SS - 1);
        const size_t idx = (((size_t)bb * NH + h) * SS + ssr) * HD + d0;
        u16 h0 = f2bf(acc[i][0]), h1 = f2bf(acc[i][1]);
        u16 h2 = f2bf(acc[i][2]), h3 = f2bf(acc[i][3]);
        u16 l0 = f2bf(acc[i][0] - bf2f(h0)), l1 = f2bf(acc[i][1] - bf2f(h1));
        u16 l2 = f2bf(acc[i][2] - bf2f(h2)), l3 = f2bf(acc[i][3] - bf2f(h3));
        *(uint2*)&ph[idx] = make_uint2((u32)h0 | ((u32)h1 << 16), (u32)h2 | ((u32)h3 << 16));
        *(uint2*)&pl[idx] = make_uint2((u32)l0 | ((u32)l1 << 16), (u32)l2 | ((u32)l3 << 16));
    }
}

// ---------------------------------------------------------------------------
// MFMA flash attention, split-bf16. 4 waves/block, 64 q-rows/block, KVBLK=64.
// Wave w owns q-rows [qt*64 + w*16, +16). Per 64-key tile:
//   S = Q K^T   : 16x16x32 mfma, A=Q (regs), B=K (LDS, swizzled), 24 mfma
//   softmax     : keys live in lane&15 -> shfl_xor{1,2,4,8} reduce
//   P -> LDS    : D-layout -> A-layout transpose via wave-private swz buffer
//   O += P V    : A=P (LDS), B=V^T (LDS, swizzled), 24 mfma
// ---------------------------------------------------------------------------
__global__ __launch_bounds__(256)
__attribute__((amdgpu_waves_per_eu(3)))
void attn_mfma_kernel(const u16* __restrict__ planes, float* __restrict__ o_all)
{
    __shared__ u16 Khi[64 * 64], Klo[64 * 64];     // [key][d]   8 KB each
    __shared__ u16 Vthi[64 * 64], Vtlo[64 * 64];   // [d][key]   8 KB each
    __shared__ u16 Pl[4][2][16 * 64];              // per-wave P hi/lo

    const int tid  = threadIdx.x;
    const int lane = tid & 63, wid = tid >> 6;
    const int l15  = lane & 15, lg = lane >> 4;
    const int qt = blockIdx.x, bh = blockIdx.y, aid = blockIdx.z;
    const int qinp  = (aid == 1) ? 1 : 0;
    const int kvinp = (aid == 0) ? 0 : 1;
    const size_t base = (size_t)bh * SS * HD;

    const u16* __restrict__ qhi = planes + (size_t)(qinp * 6 + 0) * QKV_ELEMS;
    const u16* __restrict__ qlo = qhi + QKV_ELEMS;
    const u16* __restrict__ khi = planes + (size_t)(kvinp * 6 + 2) * QKV_ELEMS;
    const u16* __restrict__ klo = khi + QKV_ELEMS;
    const u16* __restrict__ vhi = planes + (size_t)(kvinp * 6 + 4) * QKV_ELEMS;
    const u16* __restrict__ vlo = vhi + QKV_ELEMS;

    // Q fragments in registers: A-layout row=l15, k(d) = dk*32 + lg*8 + j
    const int qrow = qt * 64 + wid * 16 + l15;
    short8 qfh[2], qfl[2];
    #pragma unroll
    for (int dk = 0; dk < 2; ++dk) {
        const size_t off = base + (size_t)qrow * HD + dk * 32 + lg * 8;
        qfh[dk] = *(const short8*)&qhi[off];
        qfl[dk] = *(const short8*)&qlo[off];
    }

    const f32x4 fz = {0.f, 0.f, 0.f, 0.f};
    f32x4 O[4] = {fz, fz, fz, fz};
    float mrun[4] = {-INFINITY, -INFINITY, -INFINITY, -INFINITY};
    float lrun[4] = {0.f, 0.f, 0.f, 0.f};

    u16* __restrict__ Pw_h = &Pl[wid][0][0];
    u16* __restrict__ Pw_l = &Pl[wid][1][0];

    for (int kt0 = 0; kt0 < SS; kt0 += 64) {
        __syncthreads();   // all waves done reading previous K/Vt
        {   // ---- stage K (straight copy, swizzled) ----
            #pragma unroll
            for (int i = 0; i < 2; ++i) {
                const int c  = tid + 256 * i;          // 0..511
                const int ky = c >> 3, dg = (c & 7) * 8;
                const size_t g = base + (size_t)(kt0 + ky) * HD + dg;
                const int b = swz(ky, dg * 2);
                *(short8*)((char*)Khi + b) = *(const short8*)&khi[g];
                *(short8*)((char*)Klo + b) = *(const short8*)&klo[g];
            }
            // ---- stage V transposed: Vt[d][key], packed key-pairs ----
            const int kp = tid >> 3;                   // key pair 0..31
            const int d0 = (tid & 7) * 8;
            const size_t g0 = base + (size_t)(kt0 + 2 * kp) * HD + d0;
            short8 vah = *(const short8*)&vhi[g0];
            short8 vbh = *(const short8*)&vhi[g0 + HD];
            short8 val = *(const short8*)&vlo[g0];
            short8 vbl = *(const short8*)&vlo[g0 + HD];
            #pragma unroll
            for (int i = 0; i < 8; ++i) {
                const int d = d0 + i;
                const int b = swz(d, kp * 4);
                *(u32*)((char*)Vthi + b) = (u32)(u16)vah[i] | ((u32)(u16)vbh[i] << 16);
                *(u32*)((char*)Vtlo + b) = (u32)(u16)val[i] | ((u32)(u16)vbl[i] << 16);
            }
        }
        __syncthreads();

        // ---- S = Q K^T (split: qh*kh + qh*kl + ql*kh) ----
        f32x4 S[4] = {fz, fz, fz, fz};
        #pragma unroll
        for (int dk = 0; dk < 2; ++dk) {
            #pragma unroll
            for (int kt = 0; kt < 4; ++kt) {
                const int row = kt * 16 + l15;         // key
                const int b = swz(row, dk * 64 + lg * 16);
                short8 kfh = *(const short8*)((char*)Khi + b);
                short8 kfl = *(const short8*)((char*)Klo + b);
                S[kt] = MFMA16(qfh[dk], kfh, S[kt]);
                S[kt] = MFMA16(qfh[dk], kfl, S[kt]);
                S[kt] = MFMA16(qfl[dk], kfh, S[kt]);
            }
        }
        #pragma unroll
        for (int kt = 0; kt < 4; ++kt)
            #pragma unroll
            for (int r = 0; r < 4; ++r) S[kt][r] *= ATT_SCALE;

        // ---- online softmax; row r of D = q-row lg*4+r; keys in l15 ----
        #pragma unroll
        for (int r = 0; r < 4; ++r) {
            float tmax = fmaxf(fmaxf(S[0][r], S[1][r]), fmaxf(S[2][r], S[3][r]));
            #pragma unroll
            for (int m = 1; m <= 8; m <<= 1) tmax = fmaxf(tmax, __shfl_xor(tmax, m, 64));
            const float mnew = fmaxf(mrun[r], tmax);
            const float corr = __expf(mrun[r] - mnew);
            lrun[r] *= corr;
            #pragma unroll
            for (int dn = 0; dn < 4; ++dn) O[dn][r] *= corr;
            float psum = 0.f;
            const int qloc = lg * 4 + r;
            #pragma unroll
            for (int kt = 0; kt < 4; ++kt) {
                const float p = __expf(S[kt][r] - mnew);
                psum += p;
                const u16 phd = f2bf(p);
                const u16 pld = f2bf(p - bf2f(phd));
                const int b = swz(qloc, (kt * 16 + l15) * 2);
                *(u16*)((char*)Pw_h + b) = phd;
                *(u16*)((char*)Pw_l + b) = pld;
            }
            #pragma unroll
            for (int m = 1; m <= 8; m <<= 1) psum += __shfl_xor(psum, m, 64);
            lrun[r] += psum;
            mrun[r] = mnew;
        }

        // ---- O += P V (wave-private P; lgkmcnt ordering by compiler) ----
        #pragma unroll
        for (int ch = 0; ch < 2; ++ch) {
            const int pb = swz(l15, ch * 64 + lg * 16);
            short8 pah = *(const short8*)((char*)Pw_h + pb);
            short8 pal = *(const short8*)((char*)Pw_l + pb);
            #pragma unroll
            for (int dn = 0; dn < 4; ++dn) {
                const int drow = dn * 16 + l15;
                const int vb = swz(drow, ch * 64 + lg * 16);
                short8 vfh = *(const short8*)((char*)Vthi + vb);
                short8 vfl = *(const short8*)((char*)Vtlo + vb);
                O[dn] = MFMA16(pah, vfh, O[dn]);
                O[dn] = MFMA16(pah, vfl, O[dn]);
                O[dn] = MFMA16(pal, vfh, O[dn]);
            }
        }
    }

    // ---- epilogue: normalize, write o_all rows [attn][b][s][h*64+d] ----
    const int b = bh / NH, h = bh % NH;
    #pragma unroll
    for (int r = 0; r < 4; ++r) {
        const float inv = 1.f / lrun[r];
        const int grow = aid * MROWS + b * SS + qt * 64 + wid * 16 + lg * 4 + r;
        float* __restrict__ orow = o_all + (size_t)grow * HIDDEN + h * HD;
        #pragma unroll
        for (int dn = 0; dn < 4; ++dn) orow[dn * 16 + l15] = O[dn][r] * inv;
    }
}

// ---------------------------------------------------------------------------
// GEMM 2: out = o_all @ Wout + bout  (fp32, unchanged)
// ---------------------------------------------------------------------------
__global__ __launch_bounds__(256) void gemm_out_kernel(
    const float* __restrict__ A, const float* __restrict__ W,
    const float* __restrict__ bias, float* __restrict__ out)
{
    __shared__ float As[32][65];
    __shared__ float Bs[32][68];

    const int bm = blockIdx.x;
    const int bn = blockIdx.y;
    const int tid = threadIdx.x;
    const int tx = tid & 15, ty = tid >> 4;
    const int m0 = bm * 64, n0 = bn * 64;

    float acc[4][4] = {};

    for (int k0 = 0; k0 < HIDDEN; k0 += 32) {
        {
            const int r  = tid >> 3;
            const int kk = (tid & 7) * 4;
            #pragma unroll
            for (int rr = 0; rr < 2; ++rr) {
                const float4 v = *(const float4*)&A[(size_t)(m0 + r + rr * 32) * HIDDEN + k0 + kk];
                As[kk + 0][r + rr * 32] = v.x;
                As[kk + 1][r + rr * 32] = v.y;
                As[kk + 2][r + rr * 32] = v.z;
                As[kk + 3][r + rr * 32] = v.w;
            }
        }
        {
            const int kr = tid >> 4;
            const int nn = (tid & 15) * 4;
            #pragma unroll
            for (int rr = 0; rr < 2; ++rr) {
                *(float4*)&Bs[kr + rr * 16][nn] =
                    *(const float4*)&W[(size_t)(k0 + kr + rr * 16) * HIDDEN + n0 + nn];
            }
        }
        __syncthreads();
        #pragma unroll
        for (int k = 0; k < 32; ++k) {
            const float a0 = As[k][4 * ty + 0];
            const float a1 = As[k][4 * ty + 1];
            const float a2 = As[k][4 * ty + 2];
            const float a3 = As[k][4 * ty + 3];
            const float4 b = *(const float4*)&Bs[k][4 * tx];
            acc[0][0] = fmaf(a0, b.x, acc[0][0]); acc[0][1] = fmaf(a0, b.y, acc[0][1]);
            acc[0][2] = fmaf(a0, b.z, acc[0][2]); acc[0][3] = fmaf(a0, b.w, acc[0][3]);
            acc[1][0] = fmaf(a1, b.x, acc[1][0]); acc[1][1] = fmaf(a1, b.y, acc[1][1]);
            acc[1][2] = fmaf(a1, b.z, acc[1][2]); acc[1][3] = fmaf(a1, b.w, acc[1][3]);
            acc[2][0] = fmaf(a2, b.x, acc[2][0]); acc[2][1] = fmaf(a2, b.y, acc[2][1]);
            acc[2][2] = fmaf(a2, b.z, acc[2][2]); acc[2][3] = fmaf(a2, b.w, acc[2][3]);
            acc[3][0] = fmaf(a3, b.x, acc[3][0]); acc[3][1] = fmaf(a3, b.y, acc[3][1]);
            acc[3][2] = fmaf(a3, b.z, acc[3][2]); acc[3][3] = fmaf(a3, b.w, acc[3][3]);
        }
        __syncthreads();
    }

    const int nn = n0 + 4 * tx;
    const float4 bv = *(const float4*)&bias[nn];
    #pragma unroll
    for (int i = 0; i < 4; ++i) {
        const int m = m0 + 4 * ty + i;
        *(float4*)&out[(size_t)m * HIDDEN + nn] =
            make_float4(acc[i][0] + bv.x, acc[i][1] + bv.y,
                        acc[i][2] + bv.z, acc[i][3] + bv.w);
    }
}

// ---------------------------------------------------------------------------
extern "C" void kernel_launch(void* const* d_in, const int* in_sizes, int n_in,
                              void* d_out, int out_size, void* d_ws, size_t ws_size,
                              hipStream_t stream)
{
    const float* x    = (const float*)d_in[0];
    const float* x2   = (const float*)d_in[1];
    const float* Wqkv = (const float*)d_in[2];
    const float* Wout = (const float*)d_in[3];
    const float* bout = (const float*)d_in[4];
    float* out = (float*)d_out;

    u16*   planes = (u16*)d_ws;
    float* o_all  = (float*)((char*)d_ws + (size_t)12 * QKV_ELEMS * sizeof(u16));

    dim3 g1(M_QKV / 64, N_QKV / 64);           // 256 x 36
    gemm_qkv_kernel<<<g1, 256, 0, stream>>>(x, x2, Wqkv, planes);

    dim3 g2(SS / 64, BB * NH, 3);              // 16 x 96 x 3
    attn_mfma_kernel<<<g2, 256, 0, stream>>>(planes, o_all);

    dim3 g3(3 * MROWS / 64, HIDDEN / 64);      // 384 x 12
    gemm_out_kernel<<<g3, 256, 0, stream>>>(o_all, Wout, bout, out);
}

// Round 6
// 864.110 us; speedup vs baseline: 5.8172x; 2.0248x over previous
//
#include <hip/hip_runtime.h>
#include <math.h>

// ---------------------------------------------------------------------------
// CDAttnBlock round 6: ALL matmuls on MFMA via split-bf16 (hi/lo planes).
//   k0 conv_x   : x,x2 fp32 -> Ax hi/lo bf16 planes [16384][768]
//   k1 conv_wt  : Wqkv,Wout fp32 -> transposed hi/lo planes Wt[n][k]
//   k2 gemm_qkv : MFMA 128x128 tile, global_load_lds staging -> qkv planes
//   k3 attn     : unchanged MFMA flash attn; epilogue -> o hi/lo planes
//   k4 gemm_out : MFMA, + bias, fp32 out
//
// Workspace (bytes):
//   [0, 151.0M)            qkv planes [inp][q/k/v][hi/lo] (12 x QKV_ELEMS u16)
//   [OFF2, OFF2+50.3M)     Ax planes (k0->k2)   -- overlapped later by o
//   [OFF2+50.3M, +7.1M)    Wqkv_t planes (k1->k2) -- overlapped later by o
//   [OFF2, OFF2+75.5M)     o planes (k3->k4)
//   [OFF2+75.5M, +2.4M)    Wout_t planes (k1->k4, never overlapped)
//   peak 228.9 MB
// ---------------------------------------------------------------------------

#define HIDDEN 768
#define NH 12
#define HD 64
#define BB 8
#define SS 1024
#define ATT_SCALE 0.125f

typedef unsigned short u16;
typedef unsigned int u32;
typedef __attribute__((ext_vector_type(8))) short short8;   // 8 bf16
typedef __attribute__((ext_vector_type(4))) float f32x4;

constexpr int MROWS = BB * SS;            // 8192
constexpr int M_QKV = 2 * MROWS;          // 16384
constexpr int N_QKV = 3 * HIDDEN;         // 2304
constexpr long QKV_ELEMS = (long)BB * NH * SS * HD;    // 6,291,456
constexpr long AX_ELEMS  = (long)M_QKV * HIDDEN;       // 12,582,912
constexpr long O_ELEMS   = (long)3 * MROWS * HIDDEN;   // 18,874,368
constexpr long WQT_ELEMS = (long)N_QKV * HIDDEN;       // 1,769,472
constexpr size_t OFF2 = (size_t)12 * QKV_ELEMS * 2;    // 150,994,944 B

__device__ inline u16 f2bf(float x) {     // fp32 -> bf16 RTN
    u32 u = __float_as_uint(x);
    return (u16)((u + 0x7FFFu + ((u >> 16) & 1u)) >> 16);
}
__device__ inline float bf2f(u16 h) { return __uint_as_float(((u32)h) << 16); }
__device__ inline int swz(int row, int bcol) {      // attn LDS swizzle (G4)
    return ((row << 7) + bcol) ^ ((row & 7) << 4);
}
#define MFMA16(a, b, c) __builtin_amdgcn_mfma_f32_16x16x32_bf16(a, b, c, 0, 0, 0)

__device__ inline void gload16(const u16* g, u16* l) {
    __builtin_amdgcn_global_load_lds(
        (const __attribute__((address_space(1))) u32*)g,
        (__attribute__((address_space(3))) u32*)l, 16, 0, 0);
}

// ---------------------------------------------------------------------------
// k0: x, x2 -> Ax hi/lo planes (elementwise, vectorized)
// ---------------------------------------------------------------------------
__global__ __launch_bounds__(256) void conv_x_kernel(
    const float* __restrict__ x, const float* __restrict__ x2,
    u16* __restrict__ axh, u16* __restrict__ axl)
{
    const size_t HALF = (size_t)MROWS * HIDDEN;     // 6,291,456
    const size_t NTOT = (size_t)AX_ELEMS;
    const size_t step = (size_t)gridDim.x * 256 * 4;
    for (size_t e = ((size_t)blockIdx.x * 256 + threadIdx.x) * 4; e < NTOT; e += step) {
        const float4 v = (e < HALF) ? *(const float4*)&x[e]
                                    : *(const float4*)&x2[e - HALF];
        ushort4 h, l;
        h.x = f2bf(v.x); l.x = f2bf(v.x - bf2f(h.x));
        h.y = f2bf(v.y); l.y = f2bf(v.y - bf2f(h.y));
        h.z = f2bf(v.z); l.z = f2bf(v.z - bf2f(h.z));
        h.w = f2bf(v.w); l.w = f2bf(v.w - bf2f(h.w));
        *(ushort4*)&axh[e] = h;
        *(ushort4*)&axl[e] = l;
    }
}

// ---------------------------------------------------------------------------
// k1: Wqkv [768][2304] -> Wqt[n][k] hi/lo; Wout [768][768] -> Wot[n][k] hi/lo
// 64x64 LDS tile transpose. grid = (12, 36+12)
// ---------------------------------------------------------------------------
__global__ __launch_bounds__(256) void conv_wt_kernel(
    const float* __restrict__ Wqkv, const float* __restrict__ Wout,
    u16* __restrict__ wqt_h, u16* __restrict__ wqt_l,
    u16* __restrict__ wot_h, u16* __restrict__ wot_l)
{
    __shared__ float T[64][65];
    const int bk = blockIdx.x;
    int bn = blockIdx.y;
    const float* W; int ncols; u16 *oh, *ol;
    if (bn < 36) { W = Wqkv; ncols = N_QKV; oh = wqt_h; ol = wqt_l; }
    else         { W = Wout; ncols = HIDDEN; oh = wot_h; ol = wot_l; bn -= 36; }
    const int k0 = bk * 64, n0 = bn * 64;
    const int t = threadIdx.x;
    {   // read 64x64 fp32, coalesced
        const int r = t >> 2, c0 = (t & 3) * 16;
        #pragma unroll
        for (int q = 0; q < 4; ++q) {
            const float4 v = *(const float4*)&W[(size_t)(k0 + r) * ncols + n0 + c0 + q * 4];
            T[r][c0 + q * 4 + 0] = v.x;
            T[r][c0 + q * 4 + 1] = v.y;
            T[r][c0 + q * 4 + 2] = v.z;
            T[r][c0 + q * 4 + 3] = v.w;
        }
    }
    __syncthreads();
    {   // write transposed hi/lo, 16 k-values per thread
        const int n = t >> 2, kk0 = (t & 3) * 16;
        const size_t ob = (size_t)(n0 + n) * HIDDEN + k0 + kk0;
        #pragma unroll
        for (int q = 0; q < 4; ++q) {
            ushort4 h, l;
            float v0 = T[kk0 + q * 4 + 0][n];
            float v1 = T[kk0 + q * 4 + 1][n];
            float v2 = T[kk0 + q * 4 + 2][n];
            float v3 = T[kk0 + q * 4 + 3][n];
            h.x = f2bf(v0); l.x = f2bf(v0 - bf2f(h.x));
            h.y = f2bf(v1); l.y = f2bf(v1 - bf2f(h.y));
            h.z = f2bf(v2); l.z = f2bf(v2 - bf2f(h.z));
            h.w = f2bf(v3); l.w = f2bf(v3 - bf2f(h.w));
            *(ushort4*)&oh[ob + q * 4] = h;
            *(ushort4*)&ol[ob + q * 4] = l;
        }
    }
}

// ---------------------------------------------------------------------------
// k2: MFMA GEMM qkv. C[16384][2304] = Ax * Wqkv, split-bf16 (3 mfma/product).
// 128x128 tile, 4 waves 2x2 (each 64x64), BK=32, global_load_lds staging.
// Epilogue scatters hi/lo into q/k/v planes in [b,h,s,d] layout.
// ---------------------------------------------------------------------------
__global__ __launch_bounds__(256)
__attribute__((amdgpu_waves_per_eu(2, 2)))
void gemm_qkv_mfma(const u16* __restrict__ Agh, const u16* __restrict__ Agl,
                   const u16* __restrict__ Bgh, const u16* __restrict__ Bgl,
                   u16* __restrict__ planes)
{
    __shared__ u16 LAh[4096], LAl[4096], LBh[4096], LBl[4096];  // 8 KB each

    const int tid = threadIdx.x, lane = tid & 63, wid = tid >> 6;
    const int l15 = lane & 15, lg = lane >> 4;
    const int wr = wid >> 1, wc = wid & 1;
    const int m0 = blockIdx.x * 128, n0 = blockIdx.y * 128;

    const f32x4 fz = {0.f, 0.f, 0.f, 0.f};
    f32x4 acc[4][4] = {{fz,fz,fz,fz},{fz,fz,fz,fz},{fz,fz,fz,fz},{fz,fz,fz,fz}};

    for (int kt = 0; kt < HIDDEN / 32; ++kt) {
        const int k0 = kt * 32;
        __syncthreads();
        #pragma unroll
        for (int u = 0; u < 2; ++u) {
            const int s   = (wid * 2 + u) * 64 + lane;   // slot 0..511
            const int row = s >> 2;
            const int kc  = (s & 3) * 8;
            const int lo  = (wid * 2 + u) * 512;         // wave-uniform base
            const size_t ga = (size_t)(m0 + row) * HIDDEN + k0 + kc;
            const size_t gb = (size_t)(n0 + row) * HIDDEN + k0 + kc;
            gload16(Agh + ga, &LAh[lo]);
            gload16(Agl + ga, &LAl[lo]);
            gload16(Bgh + gb, &LBh[lo]);
            gload16(Bgl + gb, &LBl[lo]);
        }
        __syncthreads();

        short8 ah[4], al[4], bh[4], bl[4];
        #pragma unroll
        for (int i = 0; i < 4; ++i) {
            const int ro = (wr * 64 + i * 16 + l15) * 32 + lg * 8;
            ah[i] = *(const short8*)&LAh[ro];
            al[i] = *(const short8*)&LAl[ro];
        }
        #pragma unroll
        for (int j = 0; j < 4; ++j) {
            const int ro = (wc * 64 + j * 16 + l15) * 32 + lg * 8;
            bh[j] = *(const short8*)&LBh[ro];
            bl[j] = *(const short8*)&LBl[ro];
        }
        #pragma unroll
        for (int i = 0; i < 4; ++i)
            #pragma unroll
            for (int j = 0; j < 4; ++j) {
                acc[i][j] = MFMA16(ah[i], bh[j], acc[i][j]);
                acc[i][j] = MFMA16(ah[i], bl[j], acc[i][j]);
                acc[i][j] = MFMA16(al[i], bh[j], acc[i][j]);
            }
    }

    // Epilogue: C[m][n] -> planes[inp][sel][hi/lo] at [b,h,s,d]
    #pragma unroll
    for (int i = 0; i < 4; ++i) {
        #pragma unroll
        for (int r = 0; r < 4; ++r) {
            const int mr  = m0 + wr * 64 + i * 16 + lg * 4 + r;
            const int inp = (mr >= MROWS) ? 1 : 0;
            const int mm  = mr & (MROWS - 1);
            const int bb  = mm >> 10, ssr = mm & (SS - 1);
            #pragma unroll
            for (int j = 0; j < 4; ++j) {
                const int n   = n0 + wc * 64 + j * 16 + l15;
                const int sel = n / HIDDEN;
                const int hh  = (n % HIDDEN) >> 6;
                const int dd  = n & 63;
                const float v = acc[i][j][r];
                const u16 vh = f2bf(v);
                const u16 vl = f2bf(v - bf2f(vh));
                u16* ph = planes + (size_t)(inp * 6 + sel * 2) * QKV_ELEMS;
                const size_t idx = (((size_t)bb * NH + hh) * SS + ssr) * HD + dd;
                ph[idx] = vh;
                ph[QKV_ELEMS + idx] = vl;
            }
        }
    }
}

// ---------------------------------------------------------------------------
// k3: MFMA flash attention (validated round 5); epilogue -> o hi/lo planes
// ---------------------------------------------------------------------------
__global__ __launch_bounds__(256)
__attribute__((amdgpu_waves_per_eu(3)))
void attn_mfma_kernel(const u16* __restrict__ planes,
                      u16* __restrict__ o_h, u16* __restrict__ o_l)
{
    __shared__ u16 Khi[64 * 64], Klo[64 * 64];     // [key][d]   8 KB each
    __shared__ u16 Vthi[64 * 64], Vtlo[64 * 64];   // [d][key]   8 KB each
    __shared__ u16 Pl[4][2][16 * 64];              // per-wave P hi/lo

    const int tid  = threadIdx.x;
    const int lane = tid & 63, wid = tid >> 6;
    const int l15  = lane & 15, lg = lane >> 4;
    const int qt = blockIdx.x, bh = blockIdx.y, aid = blockIdx.z;
    const int qinp  = (aid == 1) ? 1 : 0;
    const int kvinp = (aid == 0) ? 0 : 1;
    const size_t base = (size_t)bh * SS * HD;

    const u16* __restrict__ qhi = planes + (size_t)(qinp * 6 + 0) * QKV_ELEMS;
    const u16* __restrict__ qlo = qhi + QKV_ELEMS;
    const u16* __restrict__ khi = planes + (size_t)(kvinp * 6 + 2) * QKV_ELEMS;
    const u16* __restrict__ klo = khi + QKV_ELEMS;
    const u16* __restrict__ vhi = planes + (size_t)(kvinp * 6 + 4) * QKV_ELEMS;
    const u16* __restrict__ vlo = vhi + QKV_ELEMS;

    const int qrow = qt * 64 + wid * 16 + l15;
    short8 qfh[2], qfl[2];
    #pragma unroll
    for (int dk = 0; dk < 2; ++dk) {
        const size_t off = base + (size_t)qrow * HD + dk * 32 + lg * 8;
        qfh[dk] = *(const short8*)&qhi[off];
        qfl[dk] = *(const short8*)&qlo[off];
    }

    const f32x4 fz = {0.f, 0.f, 0.f, 0.f};
    f32x4 O[4] = {fz, fz, fz, fz};
    float mrun[4] = {-INFINITY, -INFINITY, -INFINITY, -INFINITY};
    float lrun[4] = {0.f, 0.f, 0.f, 0.f};

    u16* __restrict__ Pw_h = &Pl[wid][0][0];
    u16* __restrict__ Pw_l = &Pl[wid][1][0];

    for (int kt0 = 0; kt0 < SS; kt0 += 64) {
        __syncthreads();
        {   // stage K (swizzled) and V transposed
            #pragma unroll
            for (int i = 0; i < 2; ++i) {
                const int c  = tid + 256 * i;
                const int ky = c >> 3, dg = (c & 7) * 8;
                const size_t g = base + (size_t)(kt0 + ky) * HD + dg;
                const int b = swz(ky, dg * 2);
                *(short8*)((char*)Khi + b) = *(const short8*)&khi[g];
                *(short8*)((char*)Klo + b) = *(const short8*)&klo[g];
            }
            const int kp = tid >> 3;
            const int d0 = (tid & 7) * 8;
            const size_t g0 = base + (size_t)(kt0 + 2 * kp) * HD + d0;
            short8 vah = *(const short8*)&vhi[g0];
            short8 vbh = *(const short8*)&vhi[g0 + HD];
            short8 val = *(const short8*)&vlo[g0];
            short8 vbl = *(const short8*)&vlo[g0 + HD];
            #pragma unroll
            for (int i = 0; i < 8; ++i) {
                const int d = d0 + i;
                const int b = swz(d, kp * 4);
                *(u32*)((char*)Vthi + b) = (u32)(u16)vah[i] | ((u32)(u16)vbh[i] << 16);
                *(u32*)((char*)Vtlo + b) = (u32)(u16)val[i] | ((u32)(u16)vbl[i] << 16);
            }
        }
        __syncthreads();

        f32x4 S[4] = {fz, fz, fz, fz};
        #pragma unroll
        for (int dk = 0; dk < 2; ++dk) {
            #pragma unroll
            for (int kt = 0; kt < 4; ++kt) {
                const int row = kt * 16 + l15;
                const int b = swz(row, dk * 64 + lg * 16);
                short8 kfh = *(const short8*)((char*)Khi + b);
                short8 kfl = *(const short8*)((char*)Klo + b);
                S[kt] = MFMA16(qfh[dk], kfh, S[kt]);
                S[kt] = MFMA16(qfh[dk], kfl, S[kt]);
                S[kt] = MFMA16(qfl[dk], kfh, S[kt]);
            }
        }
        #pragma unroll
        for (int kt = 0; kt < 4; ++kt)
            #pragma unroll
            for (int r = 0; r < 4; ++r) S[kt][r] *= ATT_SCALE;

        #pragma unroll
        for (int r = 0; r < 4; ++r) {
            float tmax = fmaxf(fmaxf(S[0][r], S[1][r]), fmaxf(S[2][r], S[3][r]));
            #pragma unroll
            for (int m = 1; m <= 8; m <<= 1) tmax = fmaxf(tmax, __shfl_xor(tmax, m, 64));
            const float mnew = fmaxf(mrun[r], tmax);
            const float corr = __expf(mrun[r] - mnew);
            lrun[r] *= corr;
            #pragma unroll
            for (int dn = 0; dn < 4; ++dn) O[dn][r] *= corr;
            float psum = 0.f;
            const int qloc = lg * 4 + r;
            #pragma unroll
            for (int kt = 0; kt < 4; ++kt) {
                const float p = __expf(S[kt][r] - mnew);
                psum += p;
                const u16 phd = f2bf(p);
                const u16 pld = f2bf(p - bf2f(phd));
                const int b = swz(qloc, (kt * 16 + l15) * 2);
                *(u16*)((char*)Pw_h + b) = phd;
                *(u16*)((char*)Pw_l + b) = pld;
            }
            #pragma unroll
            for (int m = 1; m <= 8; m <<= 1) psum += __shfl_xor(psum, m, 64);
            lrun[r] += psum;
            mrun[r] = mnew;
        }

        #pragma unroll
        for (int ch = 0; ch < 2; ++ch) {
            const int pb = swz(l15, ch * 64 + lg * 16);
            short8 pah = *(const short8*)((char*)Pw_h + pb);
            short8 pal = *(const short8*)((char*)Pw_l + pb);
            #pragma unroll
            for (int dn = 0; dn < 4; ++dn) {
                const int drow = dn * 16 + l15;
                const int vb = swz(drow, ch * 64 + lg * 16);
                short8 vfh = *(const short8*)((char*)Vthi + vb);
                short8 vfl = *(const short8*)((char*)Vtlo + vb);
                O[dn] = MFMA16(pah, vfh, O[dn]);
                O[dn] = MFMA16(pah, vfl, O[dn]);
                O[dn] = MFMA16(pal, vfh, O[dn]);
            }
        }
    }

    const int b = bh / NH, h = bh % NH;
    #pragma unroll
    for (int r = 0; r < 4; ++r) {
        const float inv = 1.f / lrun[r];
        const int grow = aid * MROWS + b * SS + qt * 64 + wid * 16 + lg * 4 + r;
        const size_t rb = (size_t)grow * HIDDEN + h * HD;
        #pragma unroll
        for (int dn = 0; dn < 4; ++dn) {
            const float v = O[dn][r] * inv;
            const u16 vh = f2bf(v);
            o_h[rb + dn * 16 + l15] = vh;
            o_l[rb + dn * 16 + l15] = f2bf(v - bf2f(vh));
        }
    }
}

// ---------------------------------------------------------------------------
// k4: MFMA GEMM out. out[24576][768] = o * Wout + bout (fp32 result)
// ---------------------------------------------------------------------------
__global__ __launch_bounds__(256)
__attribute__((amdgpu_waves_per_eu(2, 2)))
void gemm_out_mfma(const u16* __restrict__ Agh, const u16* __restrict__ Agl,
                   const u16* __restrict__ Bgh, const u16* __restrict__ Bgl,
                   const float* __restrict__ bias, float* __restrict__ out)
{
    __shared__ u16 LAh[4096], LAl[4096], LBh[4096], LBl[4096];

    const int tid = threadIdx.x, lane = tid & 63, wid = tid >> 6;
    const int l15 = lane & 15, lg = lane >> 4;
    const int wr = wid >> 1, wc = wid & 1;
    const int m0 = blockIdx.x * 128, n0 = blockIdx.y * 128;

    const f32x4 fz = {0.f, 0.f, 0.f, 0.f};
    f32x4 acc[4][4] = {{fz,fz,fz,fz},{fz,fz,fz,fz},{fz,fz,fz,fz},{fz,fz,fz,fz}};

    for (int kt = 0; kt < HIDDEN / 32; ++kt) {
        const int k0 = kt * 32;
        __syncthreads();
        #pragma unroll
        for (int u = 0; u < 2; ++u) {
            const int s   = (wid * 2 + u) * 64 + lane;
            const int row = s >> 2;
            const int kc  = (s & 3) * 8;
            const int lo  = (wid * 2 + u) * 512;
            const size_t ga = (size_t)(m0 + row) * HIDDEN + k0 + kc;
            const size_t gb = (size_t)(n0 + row) * HIDDEN + k0 + kc;
            gload16(Agh + ga, &LAh[lo]);
            gload16(Agl + ga, &LAl[lo]);
            gload16(Bgh + gb, &LBh[lo]);
            gload16(Bgl + gb, &LBl[lo]);
        }
        __syncthreads();

        short8 ah[4], al[4], bh[4], bl[4];
        #pragma unroll
        for (int i = 0; i < 4; ++i) {
            const int ro = (wr * 64 + i * 16 + l15) * 32 + lg * 8;
            ah[i] = *(const short8*)&LAh[ro];
            al[i] = *(const short8*)&LAl[ro];
        }
        #pragma unroll
        for (int j = 0; j < 4; ++j) {
            const int ro = (wc * 64 + j * 16 + l15) * 32 + lg * 8;
            bh[j] = *(const short8*)&LBh[ro];
            bl[j] = *(const short8*)&LBl[ro];
        }
        #pragma unroll
        for (int i = 0; i < 4; ++i)
            #pragma unroll
            for (int j = 0; j < 4; ++j) {
                acc[i][j] = MFMA16(ah[i], bh[j], acc[i][j]);
                acc[i][j] = MFMA16(ah[i], bl[j], acc[i][j]);
                acc[i][j] = MFMA16(al[i], bh[j], acc[i][j]);
            }
    }

    #pragma unroll
    for (int i = 0; i < 4; ++i) {
        #pragma unroll
        for (int r = 0; r < 4; ++r) {
            const int mr = m0 + wr * 64 + i * 16 + lg * 4 + r;
            #pragma unroll
            for (int j = 0; j < 4; ++j) {
                const int n = n0 + wc * 64 + j * 16 + l15;
                out[(size_t)mr * HIDDEN + n] = acc[i][j][r] + bias[n];
            }
        }
    }
}

// ---------------------------------------------------------------------------
extern "C" void kernel_launch(void* const* d_in, const int* in_sizes, int n_in,
                              void* d_out, int out_size, void* d_ws, size_t ws_size,
                              hipStream_t stream)
{
    const float* x    = (const float*)d_in[0];
    const float* x2   = (const float*)d_in[1];
    const float* Wqkv = (const float*)d_in[2];
    const float* Wout = (const float*)d_in[3];
    const float* bout = (const float*)d_in[4];
    float* out = (float*)d_out;

    char* wsb = (char*)d_ws;
    u16* planes = (u16*)wsb;                                  // 12 x QKV planes
    // region 2 (timeline-overlapped):
    u16* ax_h  = (u16*)(wsb + OFF2);                          // k0 -> k2
    u16* ax_l  = ax_h + AX_ELEMS;
    u16* wqt_h = ax_l + AX_ELEMS;                             // k1 -> k2
    u16* wqt_l = wqt_h + WQT_ELEMS;
    u16* o_h   = (u16*)(wsb + OFF2);                          // k3 -> k4 (reuses Ax/Wqt)
    u16* o_l   = o_h + O_ELEMS;
    u16* wot_h = o_l + O_ELEMS;                               // k1 -> k4 (never overlapped)
    u16* wot_l = wot_h + (long)HIDDEN * HIDDEN;

    conv_x_kernel<<<3072, 256, 0, stream>>>(x, x2, ax_h, ax_l);

    dim3 gw(12, 48);
    conv_wt_kernel<<<gw, 256, 0, stream>>>(Wqkv, Wout, wqt_h, wqt_l, wot_h, wot_l);

    dim3 g1(M_QKV / 128, N_QKV / 128);            // 128 x 18
    gemm_qkv_mfma<<<g1, 256, 0, stream>>>(ax_h, ax_l, wqt_h, wqt_l, planes);

    dim3 g2(SS / 64, BB * NH, 3);                 // 16 x 96 x 3
    attn_mfma_kernel<<<g2, 256, 0, stream>>>(planes, o_h, o_l);

    dim3 g3(3 * MROWS / 128, HIDDEN / 128);       // 192 x 6
    gemm_out_mfma<<<g3, 256, 0, stream>>>(o_h, o_l, wot_h, wot_l, bout, out);
}

// Round 7
// 712.840 us; speedup vs baseline: 7.0516x; 1.2122x over previous
//
#include <hip/hip_runtime.h>
#include <math.h>

// ---------------------------------------------------------------------------
// CDAttnBlock round 7: attention restructured.
//   - swapped QK^T (A=K, B=Q): scores row-local per lane -> 2-shfl reductions
//   - packed u32 P-writes (trunc hi/lo split), 4-way instead of 8-way conflicts
//   - 32 q-rows per wave (2 groups), 128 rows/block: staging + K-reads
//     amortized 2x, V-fragments shared across groups
// GEMMs / convs unchanged from round 6 (validated).
// ---------------------------------------------------------------------------

#define HIDDEN 768
#define NH 12
#define HD 64
#define BB 8
#define SS 1024
#define ATT_SCALE 0.125f

typedef unsigned short u16;
typedef unsigned int u32;
typedef __attribute__((ext_vector_type(8))) short short8;   // 8 bf16
typedef __attribute__((ext_vector_type(4))) float f32x4;

constexpr int MROWS = BB * SS;            // 8192
constexpr int M_QKV = 2 * MROWS;          // 16384
constexpr int N_QKV = 3 * HIDDEN;         // 2304
constexpr long QKV_ELEMS = (long)BB * NH * SS * HD;    // 6,291,456
constexpr long AX_ELEMS  = (long)M_QKV * HIDDEN;       // 12,582,912
constexpr long O_ELEMS   = (long)3 * MROWS * HIDDEN;   // 18,874,368
constexpr long WQT_ELEMS = (long)N_QKV * HIDDEN;       // 1,769,472
constexpr size_t OFF2 = (size_t)12 * QKV_ELEMS * 2;    // 150,994,944 B

__device__ inline u16 f2bf(float x) {     // fp32 -> bf16 RTN
    u32 u = __float_as_uint(x);
    return (u16)((u + 0x7FFFu + ((u >> 16) & 1u)) >> 16);
}
__device__ inline float bf2f(u16 h) { return __uint_as_float(((u32)h) << 16); }
__device__ inline int swz(int row, int bcol) {      // LDS swizzle (G4)
    return ((row << 7) + bcol) ^ ((row & 7) << 4);
}
#define MFMA16(a, b, c) __builtin_amdgcn_mfma_f32_16x16x32_bf16(a, b, c, 0, 0, 0)

__device__ inline void gload16(const u16* g, u16* l) {
    __builtin_amdgcn_global_load_lds(
        (const __attribute__((address_space(1))) u32*)g,
        (__attribute__((address_space(3))) u32*)l, 16, 0, 0);
}

// ---------------------------------------------------------------------------
// k0: x, x2 -> Ax hi/lo planes (elementwise, vectorized)
// ---------------------------------------------------------------------------
__global__ __launch_bounds__(256) void conv_x_kernel(
    const float* __restrict__ x, const float* __restrict__ x2,
    u16* __restrict__ axh, u16* __restrict__ axl)
{
    const size_t HALF = (size_t)MROWS * HIDDEN;
    const size_t NTOT = (size_t)AX_ELEMS;
    const size_t step = (size_t)gridDim.x * 256 * 4;
    for (size_t e = ((size_t)blockIdx.x * 256 + threadIdx.x) * 4; e < NTOT; e += step) {
        const float4 v = (e < HALF) ? *(const float4*)&x[e]
                                    : *(const float4*)&x2[e - HALF];
        ushort4 h, l;
        h.x = f2bf(v.x); l.x = f2bf(v.x - bf2f(h.x));
        h.y = f2bf(v.y); l.y = f2bf(v.y - bf2f(h.y));
        h.z = f2bf(v.z); l.z = f2bf(v.z - bf2f(h.z));
        h.w = f2bf(v.w); l.w = f2bf(v.w - bf2f(h.w));
        *(ushort4*)&axh[e] = h;
        *(ushort4*)&axl[e] = l;
    }
}

// ---------------------------------------------------------------------------
// k1: weight transposes -> hi/lo planes (unchanged)
// ---------------------------------------------------------------------------
__global__ __launch_bounds__(256) void conv_wt_kernel(
    const float* __restrict__ Wqkv, const float* __restrict__ Wout,
    u16* __restrict__ wqt_h, u16* __restrict__ wqt_l,
    u16* __restrict__ wot_h, u16* __restrict__ wot_l)
{
    __shared__ float T[64][65];
    const int bk = blockIdx.x;
    int bn = blockIdx.y;
    const float* W; int ncols; u16 *oh, *ol;
    if (bn < 36) { W = Wqkv; ncols = N_QKV; oh = wqt_h; ol = wqt_l; }
    else         { W = Wout; ncols = HIDDEN; oh = wot_h; ol = wot_l; bn -= 36; }
    const int k0 = bk * 64, n0 = bn * 64;
    const int t = threadIdx.x;
    {
        const int r = t >> 2, c0 = (t & 3) * 16;
        #pragma unroll
        for (int q = 0; q < 4; ++q) {
            const float4 v = *(const float4*)&W[(size_t)(k0 + r) * ncols + n0 + c0 + q * 4];
            T[r][c0 + q * 4 + 0] = v.x;
            T[r][c0 + q * 4 + 1] = v.y;
            T[r][c0 + q * 4 + 2] = v.z;
            T[r][c0 + q * 4 + 3] = v.w;
        }
    }
    __syncthreads();
    {
        const int n = t >> 2, kk0 = (t & 3) * 16;
        const size_t ob = (size_t)(n0 + n) * HIDDEN + k0 + kk0;
        #pragma unroll
        for (int q = 0; q < 4; ++q) {
            ushort4 h, l;
            float v0 = T[kk0 + q * 4 + 0][n];
            float v1 = T[kk0 + q * 4 + 1][n];
            float v2 = T[kk0 + q * 4 + 2][n];
            float v3 = T[kk0 + q * 4 + 3][n];
            h.x = f2bf(v0); l.x = f2bf(v0 - bf2f(h.x));
            h.y = f2bf(v1); l.y = f2bf(v1 - bf2f(h.y));
            h.z = f2bf(v2); l.z = f2bf(v2 - bf2f(h.z));
            h.w = f2bf(v3); l.w = f2bf(v3 - bf2f(h.w));
            *(ushort4*)&oh[ob + q * 4] = h;
            *(ushort4*)&ol[ob + q * 4] = l;
        }
    }
}

// ---------------------------------------------------------------------------
// k2: MFMA GEMM qkv (unchanged, validated round 6)
// ---------------------------------------------------------------------------
__global__ __launch_bounds__(256)
__attribute__((amdgpu_waves_per_eu(2, 2)))
void gemm_qkv_mfma(const u16* __restrict__ Agh, const u16* __restrict__ Agl,
                   const u16* __restrict__ Bgh, const u16* __restrict__ Bgl,
                   u16* __restrict__ planes)
{
    __shared__ u16 LAh[4096], LAl[4096], LBh[4096], LBl[4096];

    const int tid = threadIdx.x, lane = tid & 63, wid = tid >> 6;
    const int l15 = lane & 15, lg = lane >> 4;
    const int wr = wid >> 1, wc = wid & 1;
    const int m0 = blockIdx.x * 128, n0 = blockIdx.y * 128;

    const f32x4 fz = {0.f, 0.f, 0.f, 0.f};
    f32x4 acc[4][4] = {{fz,fz,fz,fz},{fz,fz,fz,fz},{fz,fz,fz,fz},{fz,fz,fz,fz}};

    for (int kt = 0; kt < HIDDEN / 32; ++kt) {
        const int k0 = kt * 32;
        __syncthreads();
        #pragma unroll
        for (int u = 0; u < 2; ++u) {
            const int s   = (wid * 2 + u) * 64 + lane;
            const int row = s >> 2;
            const int kc  = (s & 3) * 8;
            const int lo  = (wid * 2 + u) * 512;
            const size_t ga = (size_t)(m0 + row) * HIDDEN + k0 + kc;
            const size_t gb = (size_t)(n0 + row) * HIDDEN + k0 + kc;
            gload16(Agh + ga, &LAh[lo]);
            gload16(Agl + ga, &LAl[lo]);
            gload16(Bgh + gb, &LBh[lo]);
            gload16(Bgl + gb, &LBl[lo]);
        }
        __syncthreads();

        short8 ah[4], al[4], bh[4], bl[4];
        #pragma unroll
        for (int i = 0; i < 4; ++i) {
            const int ro = (wr * 64 + i * 16 + l15) * 32 + lg * 8;
            ah[i] = *(const short8*)&LAh[ro];
            al[i] = *(const short8*)&LAl[ro];
        }
        #pragma unroll
        for (int j = 0; j < 4; ++j) {
            const int ro = (wc * 64 + j * 16 + l15) * 32 + lg * 8;
            bh[j] = *(const short8*)&LBh[ro];
            bl[j] = *(const short8*)&LBl[ro];
        }
        #pragma unroll
        for (int i = 0; i < 4; ++i)
            #pragma unroll
            for (int j = 0; j < 4; ++j) {
                acc[i][j] = MFMA16(ah[i], bh[j], acc[i][j]);
                acc[i][j] = MFMA16(ah[i], bl[j], acc[i][j]);
                acc[i][j] = MFMA16(al[i], bh[j], acc[i][j]);
            }
    }

    #pragma unroll
    for (int i = 0; i < 4; ++i) {
        #pragma unroll
        for (int r = 0; r < 4; ++r) {
            const int mr  = m0 + wr * 64 + i * 16 + lg * 4 + r;
            const int inp = (mr >= MROWS) ? 1 : 0;
            const int mm  = mr & (MROWS - 1);
            const int bb  = mm >> 10, ssr = mm & (SS - 1);
            #pragma unroll
            for (int j = 0; j < 4; ++j) {
                const int n   = n0 + wc * 64 + j * 16 + l15;
                const int sel = n / HIDDEN;
                const int hh  = (n % HIDDEN) >> 6;
                const int dd  = n & 63;
                const float v = acc[i][j][r];
                const u16 vh = f2bf(v);
                const u16 vl = f2bf(v - bf2f(vh));
                u16* ph = planes + (size_t)(inp * 6 + sel * 2) * QKV_ELEMS;
                const size_t idx = (((size_t)bb * NH + hh) * SS + ssr) * HD + dd;
                ph[idx] = vh;
                ph[QKV_ELEMS + idx] = vl;
            }
        }
    }
}

// ---------------------------------------------------------------------------
// k3: MFMA flash attention, round-7 structure.
// 4 waves x 32 q-rows (2 groups of 16) = 128 q-rows/block. KVBLK=64.
// Swapped QK^T: S at lane(l15,lg) = score(qrow=l15, key=kt*16+lg*4+r).
// ---------------------------------------------------------------------------
__global__ __launch_bounds__(256)
__attribute__((amdgpu_waves_per_eu(2, 2)))
void attn_mfma_kernel(const u16* __restrict__ planes,
                      u16* __restrict__ o_h, u16* __restrict__ o_l)
{
    __shared__ u16 Khi[64 * 64], Klo[64 * 64];     // [key][d]   8 KB each
    __shared__ u16 Vthi[64 * 64], Vtlo[64 * 64];   // [d][key]   8 KB each
    __shared__ u16 Pbuf[4][2][2][16 * 64];         // [wave][grp][hi/lo] 32 KB

    const int tid  = threadIdx.x;
    const int lane = tid & 63, wid = tid >> 6;
    const int l15  = lane & 15, lg = lane >> 4;
    const int qt = blockIdx.x, bh = blockIdx.y, aid = blockIdx.z;
    const int qinp  = (aid == 1) ? 1 : 0;
    const int kvinp = (aid == 0) ? 0 : 1;
    const size_t base = (size_t)bh * SS * HD;

    const u16* __restrict__ qhi = planes + (size_t)(qinp * 6 + 0) * QKV_ELEMS;
    const u16* __restrict__ qlo = qhi + QKV_ELEMS;
    const u16* __restrict__ khi = planes + (size_t)(kvinp * 6 + 2) * QKV_ELEMS;
    const u16* __restrict__ klo = khi + QKV_ELEMS;
    const u16* __restrict__ vhi = planes + (size_t)(kvinp * 6 + 4) * QKV_ELEMS;
    const u16* __restrict__ vlo = vhi + QKV_ELEMS;

    // Q B-fragments: col=l15 -> qrow, k = dk*32 + lg*8 + j
    const int qb = qt * 128 + wid * 32;
    short8 qfh[2][2], qfl[2][2];                   // [group][dk]
    #pragma unroll
    for (int g = 0; g < 2; ++g)
        #pragma unroll
        for (int dk = 0; dk < 2; ++dk) {
            const size_t off = base + (size_t)(qb + g * 16 + l15) * HD + dk * 32 + lg * 8;
            qfh[g][dk] = *(const short8*)&qhi[off];
            qfl[g][dk] = *(const short8*)&qlo[off];
        }

    const f32x4 fz = {0.f, 0.f, 0.f, 0.f};
    f32x4 O[2][4] = {{fz, fz, fz, fz}, {fz, fz, fz, fz}};
    float mrun[2] = {-INFINITY, -INFINITY};
    float lrun[2] = {0.f, 0.f};

    for (int kt0 = 0; kt0 < SS; kt0 += 64) {
        __syncthreads();
        {   // ---- stage K (swizzled rows) and V transposed ----
            #pragma unroll
            for (int i = 0; i < 2; ++i) {
                const int c  = tid + 256 * i;
                const int ky = c >> 3, dg = (c & 7) * 8;
                const size_t g = base + (size_t)(kt0 + ky) * HD + dg;
                const int b = swz(ky, dg * 2);
                *(short8*)((char*)Khi + b) = *(const short8*)&khi[g];
                *(short8*)((char*)Klo + b) = *(const short8*)&klo[g];
            }
            const int kp = tid >> 3;
            const int d0 = (tid & 7) * 8;
            const size_t g0 = base + (size_t)(kt0 + 2 * kp) * HD + d0;
            short8 vah = *(const short8*)&vhi[g0];
            short8 vbh = *(const short8*)&vhi[g0 + HD];
            short8 val = *(const short8*)&vlo[g0];
            short8 vbl = *(const short8*)&vlo[g0 + HD];
            #pragma unroll
            for (int i = 0; i < 8; ++i) {
                const int d = d0 + i;
                const int b = swz(d, kp * 4);
                *(u32*)((char*)Vthi + b) = (u32)(u16)vah[i] | ((u32)(u16)vbh[i] << 16);
                *(u32*)((char*)Vtlo + b) = (u32)(u16)val[i] | ((u32)(u16)vbl[i] << 16);
            }
        }
        __syncthreads();

        // ---- S^T = K Q: K-frags shared across both groups ----
        f32x4 S[2][4] = {{fz, fz, fz, fz}, {fz, fz, fz, fz}};
        #pragma unroll
        for (int dk = 0; dk < 2; ++dk) {
            #pragma unroll
            for (int kt = 0; kt < 4; ++kt) {
                const int b = swz(kt * 16 + l15, dk * 64 + lg * 16);
                short8 kfh = *(const short8*)((char*)Khi + b);
                short8 kfl = *(const short8*)((char*)Klo + b);
                #pragma unroll
                for (int g = 0; g < 2; ++g) {
                    S[g][kt] = MFMA16(kfh, qfh[g][dk], S[g][kt]);
                    S[g][kt] = MFMA16(kfl, qfh[g][dk], S[g][kt]);
                    S[g][kt] = MFMA16(kfh, qfl[g][dk], S[g][kt]);
                }
            }
        }

        // ---- per-group softmax (row-local: 2 shfls per reduction) ----
        #pragma unroll
        for (int g = 0; g < 2; ++g) {
            float pm = -INFINITY;
            #pragma unroll
            for (int kt = 0; kt < 4; ++kt)
                #pragma unroll
                for (int r = 0; r < 4; ++r) {
                    S[g][kt][r] *= ATT_SCALE;
                    pm = fmaxf(pm, S[g][kt][r]);
                }
            pm = fmaxf(pm, __shfl_xor(pm, 16, 64));
            pm = fmaxf(pm, __shfl_xor(pm, 32, 64));
            const float mnew = fmaxf(mrun[g], pm);
            const float corr = __expf(mrun[g] - mnew);
            mrun[g] = mnew;
            lrun[g] *= corr;

            u16* __restrict__ Ph = &Pbuf[wid][g][0][0];
            u16* __restrict__ Pl = &Pbuf[wid][g][1][0];
            float psum = 0.f;
            #pragma unroll
            for (int kt = 0; kt < 4; ++kt) {
                float p0 = __expf(S[g][kt][0] - mnew);
                float p1 = __expf(S[g][kt][1] - mnew);
                float p2 = __expf(S[g][kt][2] - mnew);
                float p3 = __expf(S[g][kt][3] - mnew);
                psum += (p0 + p1) + (p2 + p3);
                // truncation hi/lo split, packed u32 (keys adjacent per lane)
                const u32 u0 = __float_as_uint(p0), u1 = __float_as_uint(p1);
                const u32 u2 = __float_as_uint(p2), u3 = __float_as_uint(p3);
                const u32 hpk0 = (u0 >> 16) | (u1 & 0xFFFF0000u);
                const u32 hpk1 = (u2 >> 16) | (u3 & 0xFFFF0000u);
                const float l0 = p0 - __uint_as_float(u0 & 0xFFFF0000u);
                const float l1 = p1 - __uint_as_float(u1 & 0xFFFF0000u);
                const float l2 = p2 - __uint_as_float(u2 & 0xFFFF0000u);
                const float l3 = p3 - __uint_as_float(u3 & 0xFFFF0000u);
                const u32 lpk0 = (__float_as_uint(l0) >> 16) | (__float_as_uint(l1) & 0xFFFF0000u);
                const u32 lpk1 = (__float_as_uint(l2) >> 16) | (__float_as_uint(l3) & 0xFFFF0000u);
                const int b0 = swz(l15, kt * 32 + lg * 8);
                *(u32*)((char*)Ph + b0)     = hpk0;
                *(u32*)((char*)Ph + b0 + 4) = hpk1;
                *(u32*)((char*)Pl + b0)     = lpk0;
                *(u32*)((char*)Pl + b0 + 4) = lpk1;
            }
            psum += __shfl_xor(psum, 16, 64);
            psum += __shfl_xor(psum, 32, 64);
            lrun[g] += psum;

            // rescale O: corr for qrow lg*4+r lives in lane (lg*4+r)
            #pragma unroll
            for (int r = 0; r < 4; ++r) {
                const float c = __shfl(corr, lg * 4 + r, 64);
                #pragma unroll
                for (int dn = 0; dn < 4; ++dn) O[g][dn][r] *= c;
            }
        }

        // ---- O += P V: V-frags shared across groups ----
        #pragma unroll
        for (int ch = 0; ch < 2; ++ch) {
            short8 vfh[4], vfl[4];
            #pragma unroll
            for (int dn = 0; dn < 4; ++dn) {
                const int vb = swz(dn * 16 + l15, ch * 64 + lg * 16);
                vfh[dn] = *(const short8*)((char*)Vthi + vb);
                vfl[dn] = *(const short8*)((char*)Vtlo + vb);
            }
            #pragma unroll
            for (int g = 0; g < 2; ++g) {
                const int pb = swz(l15, ch * 64 + lg * 16);
                short8 pah = *(const short8*)((char*)&Pbuf[wid][g][0][0] + pb);
                short8 pal = *(const short8*)((char*)&Pbuf[wid][g][1][0] + pb);
                #pragma unroll
                for (int dn = 0; dn < 4; ++dn) {
                    O[g][dn] = MFMA16(pah, vfh[dn], O[g][dn]);
                    O[g][dn] = MFMA16(pah, vfl[dn], O[g][dn]);
                    O[g][dn] = MFMA16(pal, vfh[dn], O[g][dn]);
                }
            }
        }
    }

    // ---- epilogue ----
    const int b = bh / NH, h = bh % NH;
    #pragma unroll
    for (int g = 0; g < 2; ++g) {
        const float linv = 1.f / lrun[g];
        #pragma unroll
        for (int r = 0; r < 4; ++r) {
            const float inv = __shfl(linv, lg * 4 + r, 64);
            const int grow = aid * MROWS + b * SS + qb + g * 16 + lg * 4 + r;
            const size_t rb = (size_t)grow * HIDDEN + h * HD;
            #pragma unroll
            for (int dn = 0; dn < 4; ++dn) {
                const float v = O[g][dn][r] * inv;
                const u16 vh = f2bf(v);
                o_h[rb + dn * 16 + l15] = vh;
                o_l[rb + dn * 16 + l15] = f2bf(v - bf2f(vh));
            }
        }
    }
}

// ---------------------------------------------------------------------------
// k4: MFMA GEMM out (unchanged, validated round 6)
// ---------------------------------------------------------------------------
__global__ __launch_bounds__(256)
__attribute__((amdgpu_waves_per_eu(2, 2)))
void gemm_out_mfma(const u16* __restrict__ Agh, const u16* __restrict__ Agl,
                   const u16* __restrict__ Bgh, const u16* __restrict__ Bgl,
                   const float* __restrict__ bias, float* __restrict__ out)
{
    __shared__ u16 LAh[4096], LAl[4096], LBh[4096], LBl[4096];

    const int tid = threadIdx.x, lane = tid & 63, wid = tid >> 6;
    const int l15 = lane & 15, lg = lane >> 4;
    const int wr = wid >> 1, wc = wid & 1;
    const int m0 = blockIdx.x * 128, n0 = blockIdx.y * 128;

    const f32x4 fz = {0.f, 0.f, 0.f, 0.f};
    f32x4 acc[4][4] = {{fz,fz,fz,fz},{fz,fz,fz,fz},{fz,fz,fz,fz},{fz,fz,fz,fz}};

    for (int kt = 0; kt < HIDDEN / 32; ++kt) {
        const int k0 = kt * 32;
        __syncthreads();
        #pragma unroll
        for (int u = 0; u < 2; ++u) {
            const int s   = (wid * 2 + u) * 64 + lane;
            const int row = s >> 2;
            const int kc  = (s & 3) * 8;
            const int lo  = (wid * 2 + u) * 512;
            const size_t ga = (size_t)(m0 + row) * HIDDEN + k0 + kc;
            const size_t gb = (size_t)(n0 + row) * HIDDEN + k0 + kc;
            gload16(Agh + ga, &LAh[lo]);
            gload16(Agl + ga, &LAl[lo]);
            gload16(Bgh + gb, &LBh[lo]);
            gload16(Bgl + gb, &LBl[lo]);
        }
        __syncthreads();

        short8 ah[4], al[4], bh[4], bl[4];
        #pragma unroll
        for (int i = 0; i < 4; ++i) {
            const int ro = (wr * 64 + i * 16 + l15) * 32 + lg * 8;
            ah[i] = *(const short8*)&LAh[ro];
            al[i] = *(const short8*)&LAl[ro];
        }
        #pragma unroll
        for (int j = 0; j < 4; ++j) {
            const int ro = (wc * 64 + j * 16 + l15) * 32 + lg * 8;
            bh[j] = *(const short8*)&LBh[ro];
            bl[j] = *(const short8*)&LBl[ro];
        }
        #pragma unroll
        for (int i = 0; i < 4; ++i)
            #pragma unroll
            for (int j = 0; j < 4; ++j) {
                acc[i][j] = MFMA16(ah[i], bh[j], acc[i][j]);
                acc[i][j] = MFMA16(ah[i], bl[j], acc[i][j]);
                acc[i][j] = MFMA16(al[i], bh[j], acc[i][j]);
            }
    }

    #pragma unroll
    for (int i = 0; i < 4; ++i) {
        #pragma unroll
        for (int r = 0; r < 4; ++r) {
            const int mr = m0 + wr * 64 + i * 16 + lg * 4 + r;
            #pragma unroll
            for (int j = 0; j < 4; ++j) {
                const int n = n0 + wc * 64 + j * 16 + l15;
                out[(size_t)mr * HIDDEN + n] = acc[i][j][r] + bias[n];
            }
        }
    }
}

// ---------------------------------------------------------------------------
extern "C" void kernel_launch(void* const* d_in, const int* in_sizes, int n_in,
                              void* d_out, int out_size, void* d_ws, size_t ws_size,
                              hipStream_t stream)
{
    const float* x    = (const float*)d_in[0];
    const float* x2   = (const float*)d_in[1];
    const float* Wqkv = (const float*)d_in[2];
    const float* Wout = (const float*)d_in[3];
    const float* bout = (const float*)d_in[4];
    float* out = (float*)d_out;

    char* wsb = (char*)d_ws;
    u16* planes = (u16*)wsb;
    u16* ax_h  = (u16*)(wsb + OFF2);
    u16* ax_l  = ax_h + AX_ELEMS;
    u16* wqt_h = ax_l + AX_ELEMS;
    u16* wqt_l = wqt_h + WQT_ELEMS;
    u16* o_h   = (u16*)(wsb + OFF2);
    u16* o_l   = o_h + O_ELEMS;
    u16* wot_h = o_l + O_ELEMS;
    u16* wot_l = wot_h + (long)HIDDEN * HIDDEN;

    conv_x_kernel<<<3072, 256, 0, stream>>>(x, x2, ax_h, ax_l);

    dim3 gw(12, 48);
    conv_wt_kernel<<<gw, 256, 0, stream>>>(Wqkv, Wout, wqt_h, wqt_l, wot_h, wot_l);

    dim3 g1(M_QKV / 128, N_QKV / 128);            // 128 x 18
    gemm_qkv_mfma<<<g1, 256, 0, stream>>>(ax_h, ax_l, wqt_h, wqt_l, planes);

    dim3 g2(SS / 128, BB * NH, 3);                // 8 x 96 x 3
    attn_mfma_kernel<<<g2, 256, 0, stream>>>(planes, o_h, o_l);

    dim3 g3(3 * MROWS / 128, HIDDEN / 128);       // 192 x 6
    gemm_out_mfma<<<g3, 256, 0, stream>>>(o_h, o_l, wot_h, wot_l, bout, out);
}

// Round 8
// 662.409 us; speedup vs baseline: 7.5885x; 1.0761x over previous
//
#include <hip/hip_runtime.h>
#include <math.h>

// ---------------------------------------------------------------------------
// CDAttnBlock round 8: attention micro-fixes on the validated round-7 shape.
//   Fix A: Vt LDS swizzle key ((row>>3)^row)&7 -> conflict-free V staging
//          (old key (row&7) was 8-way-conflicted on the transpose writes).
//   Fix B: XCD-aware block swizzle -> all 8 qt-blocks of a (bh,aid) share an
//          XCD's private L2 -> K/V fetched ~once per XCD instead of 8x.
// GEMMs / convs unchanged (validated round 6).
// ---------------------------------------------------------------------------

#define HIDDEN 768
#define NH 12
#define HD 64
#define BB 8
#define SS 1024
#define ATT_SCALE 0.125f

typedef unsigned short u16;
typedef unsigned int u32;
typedef __attribute__((ext_vector_type(8))) short short8;   // 8 bf16
typedef __attribute__((ext_vector_type(4))) float f32x4;

constexpr int MROWS = BB * SS;            // 8192
constexpr int M_QKV = 2 * MROWS;          // 16384
constexpr int N_QKV = 3 * HIDDEN;         // 2304
constexpr long QKV_ELEMS = (long)BB * NH * SS * HD;    // 6,291,456
constexpr long AX_ELEMS  = (long)M_QKV * HIDDEN;       // 12,582,912
constexpr long O_ELEMS   = (long)3 * MROWS * HIDDEN;   // 18,874,368
constexpr long WQT_ELEMS = (long)N_QKV * HIDDEN;       // 1,769,472
constexpr size_t OFF2 = (size_t)12 * QKV_ELEMS * 2;    // 150,994,944 B

__device__ inline u16 f2bf(float x) {     // fp32 -> bf16 RTN
    u32 u = __float_as_uint(x);
    return (u16)((u + 0x7FFFu + ((u >> 16) & 1u)) >> 16);
}
__device__ inline float bf2f(u16 h) { return __uint_as_float(((u32)h) << 16); }
__device__ inline int swz(int row, int bcol) {      // K/P swizzle (G4)
    return ((row << 7) + bcol) ^ ((row & 7) << 4);
}
// Vt swizzle: key mixes row>>3 so the transpose-write lanes (rows = i mod 8,
// row>>3 = lane) spread over 8 slots; reads (16 consecutive rows) stay 2-way.
__device__ inline int swzV(int row, int bcol) {
    return ((row << 7) + bcol) ^ ((((row >> 3) ^ row) & 7) << 4);
}
#define MFMA16(a, b, c) __builtin_amdgcn_mfma_f32_16x16x32_bf16(a, b, c, 0, 0, 0)

__device__ inline void gload16(const u16* g, u16* l) {
    __builtin_amdgcn_global_load_lds(
        (const __attribute__((address_space(1))) u32*)g,
        (__attribute__((address_space(3))) u32*)l, 16, 0, 0);
}

// ---------------------------------------------------------------------------
// k0: x, x2 -> Ax hi/lo planes (elementwise, vectorized)
// ---------------------------------------------------------------------------
__global__ __launch_bounds__(256) void conv_x_kernel(
    const float* __restrict__ x, const float* __restrict__ x2,
    u16* __restrict__ axh, u16* __restrict__ axl)
{
    const size_t HALF = (size_t)MROWS * HIDDEN;
    const size_t NTOT = (size_t)AX_ELEMS;
    const size_t step = (size_t)gridDim.x * 256 * 4;
    for (size_t e = ((size_t)blockIdx.x * 256 + threadIdx.x) * 4; e < NTOT; e += step) {
        const float4 v = (e < HALF) ? *(const float4*)&x[e]
                                    : *(const float4*)&x2[e - HALF];
        ushort4 h, l;
        h.x = f2bf(v.x); l.x = f2bf(v.x - bf2f(h.x));
        h.y = f2bf(v.y); l.y = f2bf(v.y - bf2f(h.y));
        h.z = f2bf(v.z); l.z = f2bf(v.z - bf2f(h.z));
        h.w = f2bf(v.w); l.w = f2bf(v.w - bf2f(h.w));
        *(ushort4*)&axh[e] = h;
        *(ushort4*)&axl[e] = l;
    }
}

// ---------------------------------------------------------------------------
// k1: weight transposes -> hi/lo planes (unchanged)
// ---------------------------------------------------------------------------
__global__ __launch_bounds__(256) void conv_wt_kernel(
    const float* __restrict__ Wqkv, const float* __restrict__ Wout,
    u16* __restrict__ wqt_h, u16* __restrict__ wqt_l,
    u16* __restrict__ wot_h, u16* __restrict__ wot_l)
{
    __shared__ float T[64][65];
    const int bk = blockIdx.x;
    int bn = blockIdx.y;
    const float* W; int ncols; u16 *oh, *ol;
    if (bn < 36) { W = Wqkv; ncols = N_QKV; oh = wqt_h; ol = wqt_l; }
    else         { W = Wout; ncols = HIDDEN; oh = wot_h; ol = wot_l; bn -= 36; }
    const int k0 = bk * 64, n0 = bn * 64;
    const int t = threadIdx.x;
    {
        const int r = t >> 2, c0 = (t & 3) * 16;
        #pragma unroll
        for (int q = 0; q < 4; ++q) {
            const float4 v = *(const float4*)&W[(size_t)(k0 + r) * ncols + n0 + c0 + q * 4];
            T[r][c0 + q * 4 + 0] = v.x;
            T[r][c0 + q * 4 + 1] = v.y;
            T[r][c0 + q * 4 + 2] = v.z;
            T[r][c0 + q * 4 + 3] = v.w;
        }
    }
    __syncthreads();
    {
        const int n = t >> 2, kk0 = (t & 3) * 16;
        const size_t ob = (size_t)(n0 + n) * HIDDEN + k0 + kk0;
        #pragma unroll
        for (int q = 0; q < 4; ++q) {
            ushort4 h, l;
            float v0 = T[kk0 + q * 4 + 0][n];
            float v1 = T[kk0 + q * 4 + 1][n];
            float v2 = T[kk0 + q * 4 + 2][n];
            float v3 = T[kk0 + q * 4 + 3][n];
            h.x = f2bf(v0); l.x = f2bf(v0 - bf2f(h.x));
            h.y = f2bf(v1); l.y = f2bf(v1 - bf2f(h.y));
            h.z = f2bf(v2); l.z = f2bf(v2 - bf2f(h.z));
            h.w = f2bf(v3); l.w = f2bf(v3 - bf2f(h.w));
            *(ushort4*)&oh[ob + q * 4] = h;
            *(ushort4*)&ol[ob + q * 4] = l;
        }
    }
}

// ---------------------------------------------------------------------------
// k2: MFMA GEMM qkv (unchanged, validated round 6)
// ---------------------------------------------------------------------------
__global__ __launch_bounds__(256)
__attribute__((amdgpu_waves_per_eu(2, 2)))
void gemm_qkv_mfma(const u16* __restrict__ Agh, const u16* __restrict__ Agl,
                   const u16* __restrict__ Bgh, const u16* __restrict__ Bgl,
                   u16* __restrict__ planes)
{
    __shared__ u16 LAh[4096], LAl[4096], LBh[4096], LBl[4096];

    const int tid = threadIdx.x, lane = tid & 63, wid = tid >> 6;
    const int l15 = lane & 15, lg = lane >> 4;
    const int wr = wid >> 1, wc = wid & 1;
    const int m0 = blockIdx.x * 128, n0 = blockIdx.y * 128;

    const f32x4 fz = {0.f, 0.f, 0.f, 0.f};
    f32x4 acc[4][4] = {{fz,fz,fz,fz},{fz,fz,fz,fz},{fz,fz,fz,fz},{fz,fz,fz,fz}};

    for (int kt = 0; kt < HIDDEN / 32; ++kt) {
        const int k0 = kt * 32;
        __syncthreads();
        #pragma unroll
        for (int u = 0; u < 2; ++u) {
            const int s   = (wid * 2 + u) * 64 + lane;
            const int row = s >> 2;
            const int kc  = (s & 3) * 8;
            const int lo  = (wid * 2 + u) * 512;
            const size_t ga = (size_t)(m0 + row) * HIDDEN + k0 + kc;
            const size_t gb = (size_t)(n0 + row) * HIDDEN + k0 + kc;
            gload16(Agh + ga, &LAh[lo]);
            gload16(Agl + ga, &LAl[lo]);
            gload16(Bgh + gb, &LBh[lo]);
            gload16(Bgl + gb, &LBl[lo]);
        }
        __syncthreads();

        short8 ah[4], al[4], bh[4], bl[4];
        #pragma unroll
        for (int i = 0; i < 4; ++i) {
            const int ro = (wr * 64 + i * 16 + l15) * 32 + lg * 8;
            ah[i] = *(const short8*)&LAh[ro];
            al[i] = *(const short8*)&LAl[ro];
        }
        #pragma unroll
        for (int j = 0; j < 4; ++j) {
            const int ro = (wc * 64 + j * 16 + l15) * 32 + lg * 8;
            bh[j] = *(const short8*)&LBh[ro];
            bl[j] = *(const short8*)&LBl[ro];
        }
        #pragma unroll
        for (int i = 0; i < 4; ++i)
            #pragma unroll
            for (int j = 0; j < 4; ++j) {
                acc[i][j] = MFMA16(ah[i], bh[j], acc[i][j]);
                acc[i][j] = MFMA16(ah[i], bl[j], acc[i][j]);
                acc[i][j] = MFMA16(al[i], bh[j], acc[i][j]);
            }
    }

    #pragma unroll
    for (int i = 0; i < 4; ++i) {
        #pragma unroll
        for (int r = 0; r < 4; ++r) {
            const int mr  = m0 + wr * 64 + i * 16 + lg * 4 + r;
            const int inp = (mr >= MROWS) ? 1 : 0;
            const int mm  = mr & (MROWS - 1);
            const int bb  = mm >> 10, ssr = mm & (SS - 1);
            #pragma unroll
            for (int j = 0; j < 4; ++j) {
                const int n   = n0 + wc * 64 + j * 16 + l15;
                const int sel = n / HIDDEN;
                const int hh  = (n % HIDDEN) >> 6;
                const int dd  = n & 63;
                const float v = acc[i][j][r];
                const u16 vh = f2bf(v);
                const u16 vl = f2bf(v - bf2f(vh));
                u16* ph = planes + (size_t)(inp * 6 + sel * 2) * QKV_ELEMS;
                const size_t idx = (((size_t)bb * NH + hh) * SS + ssr) * HD + dd;
                ph[idx] = vh;
                ph[QKV_ELEMS + idx] = vl;
            }
        }
    }
}

// ---------------------------------------------------------------------------
// k3: MFMA flash attention (round-7 structure + Vt-swizzle fix + XCD swizzle)
// grid: 2304 1D blocks. work = (b&7)*288 + (b>>3) keeps all 8 qt-blocks of a
// (bh,aid) on one XCD (assumes XCD = blockIdx % 8; perf-only heuristic).
// ---------------------------------------------------------------------------
__global__ __launch_bounds__(256)
__attribute__((amdgpu_waves_per_eu(2, 2)))
void attn_mfma_kernel(const u16* __restrict__ planes,
                      u16* __restrict__ o_h, u16* __restrict__ o_l)
{
    __shared__ u16 Khi[64 * 64], Klo[64 * 64];     // [key][d]   8 KB each
    __shared__ u16 Vthi[64 * 64], Vtlo[64 * 64];   // [d][key]   8 KB each
    __shared__ u16 Pbuf[4][2][2][16 * 64];         // [wave][grp][hi/lo] 32 KB

    const int tid  = threadIdx.x;
    const int lane = tid & 63, wid = tid >> 6;
    const int l15  = lane & 15, lg = lane >> 4;

    // XCD-aware bijective swizzle (Fix B)
    const int work = (blockIdx.x & 7) * 288 + (blockIdx.x >> 3);
    const int qt   = work & 7;
    const int bh   = (work >> 3) % 96;
    const int aid  = (work >> 3) / 96;

    const int qinp  = (aid == 1) ? 1 : 0;
    const int kvinp = (aid == 0) ? 0 : 1;
    const size_t base = (size_t)bh * SS * HD;

    const u16* __restrict__ qhi = planes + (size_t)(qinp * 6 + 0) * QKV_ELEMS;
    const u16* __restrict__ qlo = qhi + QKV_ELEMS;
    const u16* __restrict__ khi = planes + (size_t)(kvinp * 6 + 2) * QKV_ELEMS;
    const u16* __restrict__ klo = khi + QKV_ELEMS;
    const u16* __restrict__ vhi = planes + (size_t)(kvinp * 6 + 4) * QKV_ELEMS;
    const u16* __restrict__ vlo = vhi + QKV_ELEMS;

    // Q B-fragments: col=l15 -> qrow, k = dk*32 + lg*8 + j
    const int qb = qt * 128 + wid * 32;
    short8 qfh[2][2], qfl[2][2];                   // [group][dk]
    #pragma unroll
    for (int g = 0; g < 2; ++g)
        #pragma unroll
        for (int dk = 0; dk < 2; ++dk) {
            const size_t off = base + (size_t)(qb + g * 16 + l15) * HD + dk * 32 + lg * 8;
            qfh[g][dk] = *(const short8*)&qhi[off];
            qfl[g][dk] = *(const short8*)&qlo[off];
        }

    const f32x4 fz = {0.f, 0.f, 0.f, 0.f};
    f32x4 O[2][4] = {{fz, fz, fz, fz}, {fz, fz, fz, fz}};
    float mrun[2] = {-INFINITY, -INFINITY};
    float lrun[2] = {0.f, 0.f};

    for (int kt0 = 0; kt0 < SS; kt0 += 64) {
        __syncthreads();
        {   // ---- stage K (swz) and V transposed (swzV, conflict-free) ----
            #pragma unroll
            for (int i = 0; i < 2; ++i) {
                const int c  = tid + 256 * i;
                const int ky = c >> 3, dg = (c & 7) * 8;
                const size_t g = base + (size_t)(kt0 + ky) * HD + dg;
                const int b = swz(ky, dg * 2);
                *(short8*)((char*)Khi + b) = *(const short8*)&khi[g];
                *(short8*)((char*)Klo + b) = *(const short8*)&klo[g];
            }
            const int kp = tid >> 3;
            const int d0 = (tid & 7) * 8;
            const size_t g0 = base + (size_t)(kt0 + 2 * kp) * HD + d0;
            short8 vah = *(const short8*)&vhi[g0];
            short8 vbh = *(const short8*)&vhi[g0 + HD];
            short8 val = *(const short8*)&vlo[g0];
            short8 vbl = *(const short8*)&vlo[g0 + HD];
            #pragma unroll
            for (int i = 0; i < 8; ++i) {
                const int d = d0 + i;
                const int b = swzV(d, kp * 4);
                *(u32*)((char*)Vthi + b) = (u32)(u16)vah[i] | ((u32)(u16)vbh[i] << 16);
                *(u32*)((char*)Vtlo + b) = (u32)(u16)val[i] | ((u32)(u16)vbl[i] << 16);
            }
        }
        __syncthreads();

        // ---- S^T = K Q: K-frags shared across both groups ----
        f32x4 S[2][4] = {{fz, fz, fz, fz}, {fz, fz, fz, fz}};
        #pragma unroll
        for (int dk = 0; dk < 2; ++dk) {
            #pragma unroll
            for (int kt = 0; kt < 4; ++kt) {
                const int b = swz(kt * 16 + l15, dk * 64 + lg * 16);
                short8 kfh = *(const short8*)((char*)Khi + b);
                short8 kfl = *(const short8*)((char*)Klo + b);
                #pragma unroll
                for (int g = 0; g < 2; ++g) {
                    S[g][kt] = MFMA16(kfh, qfh[g][dk], S[g][kt]);
                    S[g][kt] = MFMA16(kfl, qfh[g][dk], S[g][kt]);
                    S[g][kt] = MFMA16(kfh, qfl[g][dk], S[g][kt]);
                }
            }
        }

        // ---- per-group softmax (row-local: 2 shfls per reduction) ----
        #pragma unroll
        for (int g = 0; g < 2; ++g) {
            float pm = -INFINITY;
            #pragma unroll
            for (int kt = 0; kt < 4; ++kt)
                #pragma unroll
                for (int r = 0; r < 4; ++r) {
                    S[g][kt][r] *= ATT_SCALE;
                    pm = fmaxf(pm, S[g][kt][r]);
                }
            pm = fmaxf(pm, __shfl_xor(pm, 16, 64));
            pm = fmaxf(pm, __shfl_xor(pm, 32, 64));
            const float mnew = fmaxf(mrun[g], pm);
            const float corr = __expf(mrun[g] - mnew);
            mrun[g] = mnew;
            lrun[g] *= corr;

            u16* __restrict__ Ph = &Pbuf[wid][g][0][0];
            u16* __restrict__ Pl = &Pbuf[wid][g][1][0];
            float psum = 0.f;
            #pragma unroll
            for (int kt = 0; kt < 4; ++kt) {
                float p0 = __expf(S[g][kt][0] - mnew);
                float p1 = __expf(S[g][kt][1] - mnew);
                float p2 = __expf(S[g][kt][2] - mnew);
                float p3 = __expf(S[g][kt][3] - mnew);
                psum += (p0 + p1) + (p2 + p3);
                const u32 u0 = __float_as_uint(p0), u1 = __float_as_uint(p1);
                const u32 u2 = __float_as_uint(p2), u3 = __float_as_uint(p3);
                const u32 hpk0 = (u0 >> 16) | (u1 & 0xFFFF0000u);
                const u32 hpk1 = (u2 >> 16) | (u3 & 0xFFFF0000u);
                const float l0 = p0 - __uint_as_float(u0 & 0xFFFF0000u);
                const float l1 = p1 - __uint_as_float(u1 & 0xFFFF0000u);
                const float l2 = p2 - __uint_as_float(u2 & 0xFFFF0000u);
                const float l3 = p3 - __uint_as_float(u3 & 0xFFFF0000u);
                const u32 lpk0 = (__float_as_uint(l0) >> 16) | (__float_as_uint(l1) & 0xFFFF0000u);
                const u32 lpk1 = (__float_as_uint(l2) >> 16) | (__float_as_uint(l3) & 0xFFFF0000u);
                const int b0 = swz(l15, kt * 32 + lg * 8);
                *(u32*)((char*)Ph + b0)     = hpk0;
                *(u32*)((char*)Ph + b0 + 4) = hpk1;
                *(u32*)((char*)Pl + b0)     = lpk0;
                *(u32*)((char*)Pl + b0 + 4) = lpk1;
            }
            psum += __shfl_xor(psum, 16, 64);
            psum += __shfl_xor(psum, 32, 64);
            lrun[g] += psum;

            #pragma unroll
            for (int r = 0; r < 4; ++r) {
                const float c = __shfl(corr, lg * 4 + r, 64);
                #pragma unroll
                for (int dn = 0; dn < 4; ++dn) O[g][dn][r] *= c;
            }
        }

        // ---- O += P V: V-frags shared across groups ----
        #pragma unroll
        for (int ch = 0; ch < 2; ++ch) {
            short8 vfh[4], vfl[4];
            #pragma unroll
            for (int dn = 0; dn < 4; ++dn) {
                const int vb = swzV(dn * 16 + l15, ch * 64 + lg * 16);
                vfh[dn] = *(const short8*)((char*)Vthi + vb);
                vfl[dn] = *(const short8*)((char*)Vtlo + vb);
            }
            #pragma unroll
            for (int g = 0; g < 2; ++g) {
                const int pb = swz(l15, ch * 64 + lg * 16);
                short8 pah = *(const short8*)((char*)&Pbuf[wid][g][0][0] + pb);
                short8 pal = *(const short8*)((char*)&Pbuf[wid][g][1][0] + pb);
                #pragma unroll
                for (int dn = 0; dn < 4; ++dn) {
                    O[g][dn] = MFMA16(pah, vfh[dn], O[g][dn]);
                    O[g][dn] = MFMA16(pah, vfl[dn], O[g][dn]);
                    O[g][dn] = MFMA16(pal, vfh[dn], O[g][dn]);
                }
            }
        }
    }

    // ---- epilogue ----
    const int b = bh / NH, h = bh % NH;
    #pragma unroll
    for (int g = 0; g < 2; ++g) {
        const float linv = 1.f / lrun[g];
        #pragma unroll
        for (int r = 0; r < 4; ++r) {
            const float inv = __shfl(linv, lg * 4 + r, 64);
            const int grow = aid * MROWS + b * SS + qb + g * 16 + lg * 4 + r;
            const size_t rb = (size_t)grow * HIDDEN + h * HD;
            #pragma unroll
            for (int dn = 0; dn < 4; ++dn) {
                const float v = O[g][dn][r] * inv;
                const u16 vh = f2bf(v);
                o_h[rb + dn * 16 + l15] = vh;
                o_l[rb + dn * 16 + l15] = f2bf(v - bf2f(vh));
            }
        }
    }
}

// ---------------------------------------------------------------------------
// k4: MFMA GEMM out (unchanged, validated round 6)
// ---------------------------------------------------------------------------
__global__ __launch_bounds__(256)
__attribute__((amdgpu_waves_per_eu(2, 2)))
void gemm_out_mfma(const u16* __restrict__ Agh, const u16* __restrict__ Agl,
                   const u16* __restrict__ Bgh, const u16* __restrict__ Bgl,
                   const float* __restrict__ bias, float* __restrict__ out)
{
    __shared__ u16 LAh[4096], LAl[4096], LBh[4096], LBl[4096];

    const int tid = threadIdx.x, lane = tid & 63, wid = tid >> 6;
    const int l15 = lane & 15, lg = lane >> 4;
    const int wr = wid >> 1, wc = wid & 1;
    const int m0 = blockIdx.x * 128, n0 = blockIdx.y * 128;

    const f32x4 fz = {0.f, 0.f, 0.f, 0.f};
    f32x4 acc[4][4] = {{fz,fz,fz,fz},{fz,fz,fz,fz},{fz,fz,fz,fz},{fz,fz,fz,fz}};

    for (int kt = 0; kt < HIDDEN / 32; ++kt) {
        const int k0 = kt * 32;
        __syncthreads();
        #pragma unroll
        for (int u = 0; u < 2; ++u) {
            const int s   = (wid * 2 + u) * 64 + lane;
            const int row = s >> 2;
            const int kc  = (s & 3) * 8;
            const int lo  = (wid * 2 + u) * 512;
            const size_t ga = (size_t)(m0 + row) * HIDDEN + k0 + kc;
            const size_t gb = (size_t)(n0 + row) * HIDDEN + k0 + kc;
            gload16(Agh + ga, &LAh[lo]);
            gload16(Agl + ga, &LAl[lo]);
            gload16(Bgh + gb, &LBh[lo]);
            gload16(Bgl + gb, &LBl[lo]);
        }
        __syncthreads();

        short8 ah[4], al[4], bh[4], bl[4];
        #pragma unroll
        for (int i = 0; i < 4; ++i) {
            const int ro = (wr * 64 + i * 16 + l15) * 32 + lg * 8;
            ah[i] = *(const short8*)&LAh[ro];
            al[i] = *(const short8*)&LAl[ro];
        }
        #pragma unroll
        for (int j = 0; j < 4; ++j) {
            const int ro = (wc * 64 + j * 16 + l15) * 32 + lg * 8;
            bh[j] = *(const short8*)&LBh[ro];
            bl[j] = *(const short8*)&LBl[ro];
        }
        #pragma unroll
        for (int i = 0; i < 4; ++i)
            #pragma unroll
            for (int j = 0; j < 4; ++j) {
                acc[i][j] = MFMA16(ah[i], bh[j], acc[i][j]);
                acc[i][j] = MFMA16(ah[i], bl[j], acc[i][j]);
                acc[i][j] = MFMA16(al[i], bh[j], acc[i][j]);
            }
    }

    #pragma unroll
    for (int i = 0; i < 4; ++i) {
        #pragma unroll
        for (int r = 0; r < 4; ++r) {
            const int mr = m0 + wr * 64 + i * 16 + lg * 4 + r;
            #pragma unroll
            for (int j = 0; j < 4; ++j) {
                const int n = n0 + wc * 64 + j * 16 + l15;
                out[(size_t)mr * HIDDEN + n] = acc[i][j][r] + bias[n];
            }
        }
    }
}

// ---------------------------------------------------------------------------
extern "C" void kernel_launch(void* const* d_in, const int* in_sizes, int n_in,
                              void* d_out, int out_size, void* d_ws, size_t ws_size,
                              hipStream_t stream)
{
    const float* x    = (const float*)d_in[0];
    const float* x2   = (const float*)d_in[1];
    const float* Wqkv = (const float*)d_in[2];
    const float* Wout = (const float*)d_in[3];
    const float* bout = (const float*)d_in[4];
    float* out = (float*)d_out;

    char* wsb = (char*)d_ws;
    u16* planes = (u16*)wsb;
    u16* ax_h  = (u16*)(wsb + OFF2);
    u16* ax_l  = ax_h + AX_ELEMS;
    u16* wqt_h = ax_l + AX_ELEMS;
    u16* wqt_l = wqt_h + WQT_ELEMS;
    u16* o_h   = (u16*)(wsb + OFF2);
    u16* o_l   = o_h + O_ELEMS;
    u16* wot_h = o_l + O_ELEMS;
    u16* wot_l = wot_h + (long)HIDDEN * HIDDEN;

    conv_x_kernel<<<3072, 256, 0, stream>>>(x, x2, ax_h, ax_l);

    dim3 gw(12, 48);
    conv_wt_kernel<<<gw, 256, 0, stream>>>(Wqkv, Wout, wqt_h, wqt_l, wot_h, wot_l);

    dim3 g1(M_QKV / 128, N_QKV / 128);            // 128 x 18
    gemm_qkv_mfma<<<g1, 256, 0, stream>>>(ax_h, ax_l, wqt_h, wqt_l, planes);

    attn_mfma_kernel<<<2304, 256, 0, stream>>>(planes, o_h, o_l);

    dim3 g3(3 * MROWS / 128, HIDDEN / 128);       // 192 x 6
    gemm_out_mfma<<<g3, 256, 0, stream>>>(o_h, o_l, wot_h, wot_l, bout, out);
}